// Round 18
// baseline (113.230 us; speedup 1.0000x reference)
//
#include <hip/hip_runtime.h>
#include <hip/hip_bf16.h>
#include <stdint.h>

#define BATCH 2
#define SEQ   2048
#define DIM   1024
#define NH    16
#define HD    64
#define MVAL  (-10000.0f)

// Native exp2 (raw v_exp_f32, no libm fixup). Fallback: e-domain with __expf.
#if __has_builtin(__builtin_amdgcn_exp2f)
#define EXP2(x) __builtin_amdgcn_exp2f(x)
#define QSCALE  (0.125f * 1.44269504f)   // fold softmax scale AND log2(e) into Q
#else
#define EXP2(x) __expf(x)
#define QSCALE  0.125f
#endif

typedef __attribute__((ext_vector_type(8))) short bf16x8;
typedef __attribute__((ext_vector_type(4))) float f32x4;
typedef unsigned short u16;

static __device__ __forceinline__ u16 f2bf(float f) {
  union { float f; uint32_t u; } c; c.f = f;
  uint32_t x = c.u;
  return (u16)((x + 0x7fffu + ((x >> 16) & 1u)) >> 16);  // RNE
}

static __device__ __forceinline__ uint32_t pk2(float a, float b) {
  __hip_bfloat162 h = __float22bfloat162_rn(make_float2(a, b));
  union { __hip_bfloat162 h; uint32_t u; } c; c.h = h;
  return c.u;
}

// swizzled byte offset within LDS tiles of 128B rows (8 x 16B chunks)
static __device__ __forceinline__ int swz128(int row, int chunk) {
  return row * 128 + (((chunk ^ (row & 7)) & 7) << 4);
}

static __device__ __forceinline__ void gload_lds16(const void* g, void* l) {
  __builtin_amdgcn_global_load_lds((const __attribute__((address_space(1))) void*)g,
                                   (__attribute__((address_space(3))) void*)l, 16, 0, 0);
}

// -------- fused prep: fp32->bf16 convert of x + both weight transposes --------
__global__ void prep_kernel(const float* __restrict__ x, u16* __restrict__ xb,
                            const float* __restrict__ Wqkv, u16* __restrict__ WqkvT,
                            const float* __restrict__ Wout, u16* __restrict__ WoutT) {
  __shared__ float tile[32][33];
  int blk = blockIdx.x, tid = threadIdx.x;
  if (blk < 4096) {
    int i = blk * 256 + tid;
    float4 v = reinterpret_cast<const float4*>(x)[i];
    reinterpret_cast<uint2*>(xb)[i] = make_uint2(pk2(v.x, v.y), pk2(v.z, v.w));
    return;
  }
  const float* in;
  u16* out;
  int C, t;
  if (blk < 4096 + 3072) { t = blk - 4096; in = Wqkv; out = WqkvT; C = 3072; }
  else                   { t = blk - 7168; in = Wout; out = WoutT; C = 1024; }
  int R = DIM;
  int c0 = (t % (C / 32)) * 32, r0 = (t / (C / 32)) * 32;
  int tx = tid & 31, ty = tid >> 5;
#pragma unroll
  for (int i = 0; i < 32; i += 8)
    tile[ty + i][tx] = in[(size_t)(r0 + ty + i) * C + c0 + tx];
  __syncthreads();
#pragma unroll
  for (int i = 0; i < 32; i += 8)
    out[(size_t)(c0 + ty + i) * R + r0 + tx] = f2bf(tile[tx][ty + i]);
}

// ---------------- bf16 GEMM: C = A[M,K] * Bt[N,K]^T + bias ----------------
// Swizzled LDS (pre-swizzled gload_lds source + swizzled ds_read_b128).
// SWAPPED mfma operands: lane's acc quad holds 4 consecutive n -> packed stores.
// EPI==0: Q (x QSCALE) / K head-split [bh][s][d] bf16 (8B stores);
//         V written TRANSPOSED [bh][d][s] directly (2B stores, 32B lane-runs).
// EPI==1: plain fp32 [M][N], 16B stores
template <int EPI>
__global__ __launch_bounds__(256, 2) void gemm_bt_kernel(
    const u16* __restrict__ A, const u16* __restrict__ Bt,
    const float* __restrict__ bias, float* __restrict__ Cout,
    u16* __restrict__ Qo, u16* __restrict__ Ko, u16* __restrict__ Vto,
    int M, int N, int K) {
  __shared__ __align__(16) char lds[32768];
  char* As = lds;            // 128 rows x 64 bf16, swizzled
  char* Bs = lds + 16384;
  int tid = threadIdx.x;
  int lane = tid & 63, l15 = lane & 15, l4 = lane >> 4;
  int w = tid >> 6, wr = w >> 1, wc = w & 1;
  int m0 = blockIdx.y * 128, n0 = blockIdx.x * 128;
  int srow = tid >> 3, sch = tid & 7;
  int sc_swz = ((sch ^ (srow & 7)) << 3);  // pre-swizzled source chunk (u16 units)

  const u16* Ap = A + (size_t)(m0 + srow) * K + sc_swz;
  const u16* Bp = Bt + (size_t)(n0 + srow) * K + sc_swz;

  f32x4 acc[4][4] = {};  // acc[nj][mi]: quad holds 4 consecutive n

  for (int k0 = 0; k0 < K; k0 += 64) {
    __syncthreads();
#pragma unroll
    for (int i = 0; i < 4; i++) {
      gload_lds16(Ap + (size_t)i * 32 * K + k0, As + i * 4096 + tid * 16);
      gload_lds16(Bp + (size_t)i * 32 * K + k0, Bs + i * 4096 + tid * 16);
    }
    __syncthreads();
#pragma unroll
    for (int ks = 0; ks < 2; ks++) {
      int ch = ks * 4 + l4;
      bf16x8 af[4], bfv[4];
#pragma unroll
      for (int mi = 0; mi < 4; mi++)
        af[mi] = *reinterpret_cast<const bf16x8*>(As + swz128(wr * 64 + mi * 16 + l15, ch));
#pragma unroll
      for (int nj = 0; nj < 4; nj++)
        bfv[nj] = *reinterpret_cast<const bf16x8*>(Bs + swz128(wc * 64 + nj * 16 + l15, ch));
#pragma unroll
      for (int nj = 0; nj < 4; nj++)
#pragma unroll
        for (int mi = 0; mi < 4; mi++)
          acc[nj][mi] = __builtin_amdgcn_mfma_f32_16x16x32_bf16(bfv[nj], af[mi], acc[nj][mi], 0, 0, 0);
    }
  }

  // epilogue: lane holds C[m][nb..nb+3], m = ..+l15, nb = ..+l4*4
#pragma unroll
  for (int nj = 0; nj < 4; nj++) {
    int nb = n0 + wc * 64 + nj * 16 + l4 * 4;
    float4 bv = *reinterpret_cast<const float4*>(bias + nb);
#pragma unroll
    for (int mi = 0; mi < 4; mi++) {
      int m = m0 + wr * 64 + mi * 16 + l15;
      f32x4 a = acc[nj][mi];
      float v0 = a[0] + bv.x, v1 = a[1] + bv.y, v2 = a[2] + bv.z, v3 = a[3] + bv.w;
      if (EPI == 1) {
        *reinterpret_cast<float4*>(Cout + (size_t)m * N + nb) = make_float4(v0, v1, v2, v3);
      } else {
        int b = m >> 11, s = m & 2047;
        int sec = nb >> 10, c = nb & 1023, h = c >> 6, d = c & 63;  // sec,h wave-uniform
        size_t bh = (size_t)(b * NH + h);
        if (sec == 0) {
          *reinterpret_cast<uint2*>(Qo + (bh * SEQ + s) * HD + d) =
              make_uint2(pk2(v0 * QSCALE, v1 * QSCALE), pk2(v2 * QSCALE, v3 * QSCALE));
        } else if (sec == 1) {
          *reinterpret_cast<uint2*>(Ko + (bh * SEQ + s) * HD + d) =
              make_uint2(pk2(v0, v1), pk2(v2, v3));
        } else {
          // V transposed: [bh][d][s]; lanes (l15 = s) make 32B contiguous runs
          u16* vt = Vto + (bh * HD + d) * SEQ + s;
          vt[0]       = f2bf(v0);
          vt[SEQ]     = f2bf(v1);
          vt[2 * SEQ] = f2bf(v2);
          vt[3 * SEQ] = f2bf(v3);
        }
      }
    }
  }
}

// ------- causal flash attention: 64-wide KV tiles, 40KB LDS, 4 blocks/CU -------
// 1024 blocks x 256 thr, ALL co-resident (4/CU = 16 waves/CU). P scratch is
// 2KB/wave (16 rows): mi-halves written/read sequentially (per-wave LDS ops are
// in-order, no extra sync). qt remapped so each CU's 4 blocks (blk = c mod 256)
// sum to a constant 62 step-slots: qt = (3-k)*8 + (k odd ? 7-g : g).
// Waves: sub = q 32-half, par = kv 32-half. Double-buffered gload_lds staging.
__global__ __launch_bounds__(256, 4) void attn_kernel(
    const u16* __restrict__ Q, const u16* __restrict__ K,
    const u16* __restrict__ Vt, u16* __restrict__ O) {
  __shared__ __align__(16) char lds[40960];  // K 2x8K | V 2x8K | P 4x2K
  int tid = threadIdx.x, lane = tid & 63, w = tid >> 6;
  int l15 = lane & 15, l4 = lane >> 4;
  int sub = w & 1, par = w >> 1;
  int blk = blockIdx.x;
  int bh = (blk & 7) * 4 + ((blk >> 3) & 3);   // XCD-clustered; same bh per CU slot
  int g = (blk >> 5) & 7, k = blk >> 8;
  int qt = ((3 - k) << 3) | ((k & 1) ? (7 - g) : g);  // balanced per-CU load, heavy first
  const u16* Qh = Q + (size_t)bh * SEQ * HD;
  const u16* Kh = K + (size_t)bh * SEQ * HD;
  const u16* Vh = Vt + (size_t)bh * HD * SEQ;
  char* Pw = lds + 32768 + w * 2048;   // 16 rows x 128B per wave
  int srow = tid >> 3, sch = tid & 7;
  int b_ = bh >> 4, h_ = bh & 15;

  bf16x8 onesf;
#pragma unroll
  for (int j = 0; j < 8; j++) onesf[j] = (short)0x3F80;  // bf16 1.0

  // stage one 64-wide K tile + V^T tile (64 rows x 128B each)
  auto stageKV = [&](int b, int T) {
    const u16* Kt = Kh + (size_t)T * 64 * HD;
    const u16* Vs = Vh + (size_t)T * 64;
    char* Kb = lds + b * 8192;
    char* Vb = lds + 16384 + b * 8192;
#pragma unroll
    for (int i = 0; i < 2; i++) {
      int row = i * 32 + srow;
      int c = (sch ^ (row & 7)) << 3;
      gload_lds16(Kt + (size_t)row * HD + c, Kb + row * 128 + sch * 16);
      gload_lds16(Vs + (size_t)row * SEQ + c, Vb + row * 128 + sch * 16);
    }
  };

  int nT = qt + 1;                      // 64-wide kv tiles covering [0,(qt+1)*64)
  int qb = qt * 64 + sub * 32;

  bf16x8 qf[2][2];
#pragma unroll
  for (int mi = 0; mi < 2; mi++)
#pragma unroll
    for (int ks = 0; ks < 2; ks++)
      qf[mi][ks] = *reinterpret_cast<const bf16x8*>(
          Qh + (size_t)(qb + mi * 16 + l15) * HD + ks * 32 + l4 * 8);

  float mrun[2] = {-1e30f, -1e30f};
  f32x4 oacc[4][2] = {};
  f32x4 acc_l[2] = {};

  int buf = 0;
  stageKV(0, 0);
  __syncthreads();   // tile 0 resident

  for (int T = 0; T < nT; T++) {
    if (T + 1 < nT) stageKV(buf ^ 1, T + 1);
    char* Kw = lds + buf * 8192;
    char* Vw = lds + 16384 + buf * 8192;
    int kvb = T * 64 + par * 32;

    // S^T = K . Q^T  (D: row = kv = l4*4+r within nj tile, col = q = l15)
    f32x4 s[2][2] = {};
    __builtin_amdgcn_s_setprio(1);
#pragma unroll
    for (int ks = 0; ks < 2; ks++)
#pragma unroll
      for (int nj = 0; nj < 2; nj++) {
        bf16x8 kf = *reinterpret_cast<const bf16x8*>(
            Kw + swz128(par * 32 + nj * 16 + l15, ks * 4 + l4));
#pragma unroll
        for (int mi = 0; mi < 2; mi++)
          s[nj][mi] = __builtin_amdgcn_mfma_f32_16x16x32_bf16(kf, qf[mi][ks], s[nj][mi], 0, 0, 0);
      }
    __builtin_amdgcn_s_setprio(0);

    // causal mask: only tiles touching the diagonal
    if (kvb + 31 > qb) {
#pragma unroll
      for (int nj = 0; nj < 2; nj++)
#pragma unroll
        for (int mi = 0; mi < 2; mi++) {
          int qg = qb + mi * 16 + l15;
#pragma unroll
          for (int r = 0; r < 4; r++) {
            int kg = kvb + nj * 16 + l4 * 4 + r;
            if (kg > qg) s[nj][mi][r] = MVAL;
          }
        }
    }

    // tile row-max (q lane-local, reduce across l4: 2 shuffles)
    float mt[2];
#pragma unroll
    for (int mi = 0; mi < 2; mi++) {
      float m = s[0][mi][0];
#pragma unroll
      for (int nj = 0; nj < 2; nj++)
#pragma unroll
        for (int r = 0; r < 4; r++) m = fmaxf(m, s[nj][mi][r]);
      m = fmaxf(m, __shfl_xor(m, 16));
      m = fmaxf(m, __shfl_xor(m, 32));
      mt[mi] = m;
    }

    // defer-max: skip rescale when running max unchanged (exact, THR=0)
    if (!__all((mt[0] <= mrun[0]) & (mt[1] <= mrun[1]))) {
#pragma unroll
      for (int mi = 0; mi < 2; mi++) {
        float mnew = fmaxf(mrun[mi], mt[mi]);
        float alpha = EXP2(mrun[mi] - mnew);
        mrun[mi] = mnew;
#pragma unroll
        for (int nd = 0; nd < 4; nd++)
#pragma unroll
          for (int r = 0; r < 4; r++) oacc[nd][mi][r] *= alpha;
#pragma unroll
        for (int r = 0; r < 4; r++) acc_l[mi][r] *= alpha;
      }
    }

    // P halves sequentially through the 2KB per-wave buffer (in-order LDS ops)
    bf16x8 pf[2];
#pragma unroll
    for (int mi = 0; mi < 2; mi++) {
#pragma unroll
      for (int nj = 0; nj < 2; nj++) {
        float p0 = EXP2(s[nj][mi][0] - mrun[mi]);
        float p1 = EXP2(s[nj][mi][1] - mrun[mi]);
        float p2 = EXP2(s[nj][mi][2] - mrun[mi]);
        float p3 = EXP2(s[nj][mi][3] - mrun[mi]);
        int chunk = nj * 2 + (l4 >> 1);
        char* dst = Pw + l15 * 128 + (((chunk ^ (l15 & 7)) & 7) << 4) + (l4 & 1) * 8;
        *reinterpret_cast<uint2*>(dst) = make_uint2(pk2(p0, p1), pk2(p2, p3));
      }
      asm volatile("s_waitcnt lgkmcnt(0)" ::: "memory");
      __builtin_amdgcn_sched_barrier(0);
      pf[mi] = *reinterpret_cast<const bf16x8*>(Pw + swz128(l15, l4));
    }

    // O^T += V^T . P^T ; row-sums via ones-MFMA into acc_l
    __builtin_amdgcn_s_setprio(1);
#pragma unroll
    for (int nd = 0; nd < 4; nd++) {
      bf16x8 vf = *reinterpret_cast<const bf16x8*>(
          Vw + swz128(nd * 16 + l15, par * 4 + l4));
#pragma unroll
      for (int mi = 0; mi < 2; mi++)
        oacc[nd][mi] = __builtin_amdgcn_mfma_f32_16x16x32_bf16(vf, pf[mi], oacc[nd][mi], 0, 0, 0);
    }
#pragma unroll
    for (int mi = 0; mi < 2; mi++)
      acc_l[mi] = __builtin_amdgcn_mfma_f32_16x16x32_bf16(onesf, pf[mi], acc_l[mi], 0, 0, 0);
    __builtin_amdgcn_s_setprio(0);

    __syncthreads();  // drains vmcnt: tile T+1 resident
    buf ^= 1;
  }

  // ---- cross-parity merge: Xo spans both (dead) K buffers, Xml in dead V ----
  char* Xo = lds;                       // 64 rows x 256B fp32
  float* Xml = (float*)(lds + 16384);   // 64 x (m,l)
  if (par == 1) {
#pragma unroll
    for (int mi = 0; mi < 2; mi++) {
      int row = sub * 32 + mi * 16 + l15;
      if (l4 == 0) {
        Xml[row * 2] = mrun[mi];
        Xml[row * 2 + 1] = acc_l[mi][0];
      }
#pragma unroll
      for (int nd = 0; nd < 4; nd++)
        *reinterpret_cast<f32x4*>(Xo + row * 256 + (((nd * 4 + l4) ^ (row & 7)) << 4)) =
            oacc[nd][mi];
    }
  }
  __syncthreads();
  if (par == 0) {
#pragma unroll
    for (int mi = 0; mi < 2; mi++) {
      int row = sub * 32 + mi * 16 + l15;
      float mB = Xml[row * 2], lB = Xml[row * 2 + 1];
      float m = fmaxf(mrun[mi], mB);
      float wA = EXP2(mrun[mi] - m), wB = EXP2(mB - m);
      float linv = 1.0f / (acc_l[mi][0] * wA + lB * wB);
      float fA = wA * linv, fB = wB * linv;
      u16* orow = O + ((size_t)b_ * SEQ + qt * 64 + sub * 32 + mi * 16 + l15) * DIM + h_ * HD;
#pragma unroll
      for (int nd = 0; nd < 4; nd++) {
        f32x4 ob = *reinterpret_cast<const f32x4*>(
            Xo + row * 256 + (((nd * 4 + l4) ^ (row & 7)) << 4));
        float o0 = oacc[nd][mi][0] * fA + ob[0] * fB;
        float o1 = oacc[nd][mi][1] * fA + ob[1] * fB;
        float o2 = oacc[nd][mi][2] * fA + ob[2] * fB;
        float o3 = oacc[nd][mi][3] * fA + ob[3] * fB;
        *reinterpret_cast<uint2*>(orow + nd * 16 + l4 * 4) = make_uint2(pk2(o0, o1), pk2(o2, o3));
      }
    }
  }
}

extern "C" void kernel_launch(void* const* d_in, const int* in_sizes, int n_in,
                              void* d_out, int out_size, void* d_ws, size_t ws_size,
                              hipStream_t stream) {
  const float* x     = (const float*)d_in[0];
  const float* W_qkv = (const float*)d_in[1];
  const float* b_qkv = (const float*)d_in[2];
  const float* W_out = (const float*)d_in[3];
  const float* b_out = (const float*)d_in[4];
  float* out = (float*)d_out;
  char* ws = (char*)d_ws;

  // ws layout (bytes)
  u16* xb    = (u16*)(ws);                               // 8 MB  [4096][1024]
  u16* WqkvT = (u16*)(ws + 8388608);                     // 6 MB  [3072][1024]
  u16* WoutT = (u16*)(ws + 8388608 + 6291456);           // 2 MB  [1024][1024]
  u16* Qb    = (u16*)(ws + 16777216);                    // 8 MB  [32][2048][64]
  u16* Kb    = (u16*)(ws + 16777216 + 8388608);          // 8 MB  [32][2048][64]
  u16* Vtb   = (u16*)(ws + 16777216 + 2 * 8388608);      // 8 MB  [32][64][2048]
  u16* Ob    = (u16*)(ws + 16777216 + 3 * 8388608);      // 8 MB  [4096][1024]

  prep_kernel<<<4096 + 3072 + 1024, 256, 0, stream>>>(x, xb, W_qkv, WqkvT, W_out, WoutT);
  gemm_bt_kernel<0><<<dim3(3 * DIM / 128, BATCH * SEQ / 128), 256, 0, stream>>>(
      xb, WqkvT, b_qkv, nullptr, Qb, Kb, Vtb, BATCH * SEQ, 3 * DIM, DIM);
  attn_kernel<<<1024, 256, 0, stream>>>(Qb, Kb, Vtb, Ob);
  gemm_bt_kernel<1><<<dim3(DIM / 128, BATCH * SEQ / 128), 256, 0, stream>>>(
      Ob, WoutT, b_out, out, nullptr, nullptr, nullptr, BATCH * SEQ, DIM, DIM);
}

// Round 19
// 110.841 us; speedup vs baseline: 1.0216x; 1.0216x over previous
//
#include <hip/hip_runtime.h>
#include <hip/hip_bf16.h>
#include <stdint.h>

#define BATCH 2
#define SEQ   2048
#define DIM   1024
#define NH    16
#define HD    64
#define MVAL  (-10000.0f)

// Native exp2 (raw v_exp_f32, no libm fixup). Fallback: e-domain with __expf.
#if __has_builtin(__builtin_amdgcn_exp2f)
#define EXP2(x) __builtin_amdgcn_exp2f(x)
#define QSCALE  (0.125f * 1.44269504f)   // fold softmax scale AND log2(e) into Q
#else
#define EXP2(x) __expf(x)
#define QSCALE  0.125f
#endif

typedef __attribute__((ext_vector_type(8))) short bf16x8;
typedef __attribute__((ext_vector_type(4))) float f32x4;
typedef unsigned short u16;

static __device__ __forceinline__ u16 f2bf(float f) {
  union { float f; uint32_t u; } c; c.f = f;
  uint32_t x = c.u;
  return (u16)((x + 0x7fffu + ((x >> 16) & 1u)) >> 16);  // RNE
}

static __device__ __forceinline__ uint32_t pk2(float a, float b) {
  __hip_bfloat162 h = __float22bfloat162_rn(make_float2(a, b));
  union { __hip_bfloat162 h; uint32_t u; } c; c.h = h;
  return c.u;
}

// swizzled byte offset within LDS tiles of 128B rows (8 x 16B chunks)
static __device__ __forceinline__ int swz128(int row, int chunk) {
  return row * 128 + (((chunk ^ (row & 7)) & 7) << 4);
}

static __device__ __forceinline__ void gload_lds16(const void* g, void* l) {
  __builtin_amdgcn_global_load_lds((const __attribute__((address_space(1))) void*)g,
                                   (__attribute__((address_space(3))) void*)l, 16, 0, 0);
}

// -------- fused prep: fp32->bf16 convert of x + both weight transposes --------
__global__ void prep_kernel(const float* __restrict__ x, u16* __restrict__ xb,
                            const float* __restrict__ Wqkv, u16* __restrict__ WqkvT,
                            const float* __restrict__ Wout, u16* __restrict__ WoutT) {
  __shared__ float tile[32][33];
  int blk = blockIdx.x, tid = threadIdx.x;
  if (blk < 4096) {
    int i = blk * 256 + tid;
    float4 v = reinterpret_cast<const float4*>(x)[i];
    reinterpret_cast<uint2*>(xb)[i] = make_uint2(pk2(v.x, v.y), pk2(v.z, v.w));
    return;
  }
  const float* in;
  u16* out;
  int C, t;
  if (blk < 4096 + 3072) { t = blk - 4096; in = Wqkv; out = WqkvT; C = 3072; }
  else                   { t = blk - 7168; in = Wout; out = WoutT; C = 1024; }
  int R = DIM;
  int c0 = (t % (C / 32)) * 32, r0 = (t / (C / 32)) * 32;
  int tx = tid & 31, ty = tid >> 5;
#pragma unroll
  for (int i = 0; i < 32; i += 8)
    tile[ty + i][tx] = in[(size_t)(r0 + ty + i) * C + c0 + tx];
  __syncthreads();
#pragma unroll
  for (int i = 0; i < 32; i += 8)
    out[(size_t)(c0 + ty + i) * R + r0 + tx] = f2bf(tile[tx][ty + i]);
}

// ---------------- bf16 GEMM: C = A[M,K] * Bt[N,K]^T + bias ----------------
// Swizzled LDS (pre-swizzled gload_lds source + swizzled ds_read_b128).
// SWAPPED mfma operands: lane's acc quad holds 4 consecutive n -> packed stores.
// EPI==0: Q (x QSCALE) / K head-split [bh][s][d] bf16 (8B stores);
//         V written TRANSPOSED [bh][d][s] directly (2B stores, 32B lane-runs).
// EPI==1: plain fp32 [M][N], 16B stores
template <int EPI>
__global__ __launch_bounds__(256, 2) void gemm_bt_kernel(
    const u16* __restrict__ A, const u16* __restrict__ Bt,
    const float* __restrict__ bias, float* __restrict__ Cout,
    u16* __restrict__ Qo, u16* __restrict__ Ko, u16* __restrict__ Vto,
    int M, int N, int K) {
  __shared__ __align__(16) char lds[32768];
  char* As = lds;            // 128 rows x 64 bf16, swizzled
  char* Bs = lds + 16384;
  int tid = threadIdx.x;
  int lane = tid & 63, l15 = lane & 15, l4 = lane >> 4;
  int w = tid >> 6, wr = w >> 1, wc = w & 1;
  int m0 = blockIdx.y * 128, n0 = blockIdx.x * 128;
  int srow = tid >> 3, sch = tid & 7;
  int sc_swz = ((sch ^ (srow & 7)) << 3);  // pre-swizzled source chunk (u16 units)

  const u16* Ap = A + (size_t)(m0 + srow) * K + sc_swz;
  const u16* Bp = Bt + (size_t)(n0 + srow) * K + sc_swz;

  f32x4 acc[4][4] = {};  // acc[nj][mi]: quad holds 4 consecutive n

  for (int k0 = 0; k0 < K; k0 += 64) {
    __syncthreads();
#pragma unroll
    for (int i = 0; i < 4; i++) {
      gload_lds16(Ap + (size_t)i * 32 * K + k0, As + i * 4096 + tid * 16);
      gload_lds16(Bp + (size_t)i * 32 * K + k0, Bs + i * 4096 + tid * 16);
    }
    __syncthreads();
#pragma unroll
    for (int ks = 0; ks < 2; ks++) {
      int ch = ks * 4 + l4;
      bf16x8 af[4], bfv[4];
#pragma unroll
      for (int mi = 0; mi < 4; mi++)
        af[mi] = *reinterpret_cast<const bf16x8*>(As + swz128(wr * 64 + mi * 16 + l15, ch));
#pragma unroll
      for (int nj = 0; nj < 4; nj++)
        bfv[nj] = *reinterpret_cast<const bf16x8*>(Bs + swz128(wc * 64 + nj * 16 + l15, ch));
#pragma unroll
      for (int nj = 0; nj < 4; nj++)
#pragma unroll
        for (int mi = 0; mi < 4; mi++)
          acc[nj][mi] = __builtin_amdgcn_mfma_f32_16x16x32_bf16(bfv[nj], af[mi], acc[nj][mi], 0, 0, 0);
    }
  }

  // epilogue: lane holds C[m][nb..nb+3], m = ..+l15, nb = ..+l4*4
#pragma unroll
  for (int nj = 0; nj < 4; nj++) {
    int nb = n0 + wc * 64 + nj * 16 + l4 * 4;
    float4 bv = *reinterpret_cast<const float4*>(bias + nb);
#pragma unroll
    for (int mi = 0; mi < 4; mi++) {
      int m = m0 + wr * 64 + mi * 16 + l15;
      f32x4 a = acc[nj][mi];
      float v0 = a[0] + bv.x, v1 = a[1] + bv.y, v2 = a[2] + bv.z, v3 = a[3] + bv.w;
      if (EPI == 1) {
        *reinterpret_cast<float4*>(Cout + (size_t)m * N + nb) = make_float4(v0, v1, v2, v3);
      } else {
        int b = m >> 11, s = m & 2047;
        int sec = nb >> 10, c = nb & 1023, h = c >> 6, d = c & 63;  // sec,h wave-uniform
        size_t bh = (size_t)(b * NH + h);
        if (sec == 0) {
          *reinterpret_cast<uint2*>(Qo + (bh * SEQ + s) * HD + d) =
              make_uint2(pk2(v0 * QSCALE, v1 * QSCALE), pk2(v2 * QSCALE, v3 * QSCALE));
        } else if (sec == 1) {
          *reinterpret_cast<uint2*>(Ko + (bh * SEQ + s) * HD + d) =
              make_uint2(pk2(v0, v1), pk2(v2, v3));
        } else {
          // V transposed: [bh][d][s]; lanes (l15 = s) make 32B contiguous runs
          u16* vt = Vto + (bh * HD + d) * SEQ + s;
          vt[0]       = f2bf(v0);
          vt[SEQ]     = f2bf(v1);
          vt[2 * SEQ] = f2bf(v2);
          vt[3 * SEQ] = f2bf(v3);
        }
      }
    }
  }
}

// ------- causal flash attention: 64-wide KV tiles, 3 blocks/CU + deferred PV -------
// 1024 blocks x 256 thr (r17 config: 48KB LDS, heavy-first qt). Wave = sub (q
// 32-half) x par (kv 32-half). Double-buffered gload_lds staging, 1 barrier/step.
// DEFERRED PV: P/V fragments of tile T carried in regs across the barrier; PV(T)
// issues at step T+1's top (pure-reg MFMA under QK's ds_reads). Exact reordering
// (r10-verified): oacc/acc_l rescale at step T covers PV(T-1) applied at step-T top.
__global__ __launch_bounds__(256, 3) void attn_kernel(
    const u16* __restrict__ Q, const u16* __restrict__ K,
    const u16* __restrict__ Vt, u16* __restrict__ O) {
  __shared__ __align__(16) char lds[49152];  // K 2x8K | V 2x8K | P 4x4K
  int tid = threadIdx.x, lane = tid & 63, w = tid >> 6;
  int l15 = lane & 15, l4 = lane >> 4;
  int sub = w & 1, par = w >> 1;
  int blk = blockIdx.x;
  int bh = (blk & 7) * 4 + ((blk >> 3) & 3);   // XCD-clustered
  int qt = 31 - (blk >> 5);                    // heavy tiles dispatch first
  const u16* Qh = Q + (size_t)bh * SEQ * HD;
  const u16* Kh = K + (size_t)bh * SEQ * HD;
  const u16* Vh = Vt + (size_t)bh * HD * SEQ;
  char* Pw = lds + 32768 + w * 4096;
  int srow = tid >> 3, sch = tid & 7;
  int b_ = bh >> 4, h_ = bh & 15;

  bf16x8 onesf;
#pragma unroll
  for (int j = 0; j < 8; j++) onesf[j] = (short)0x3F80;  // bf16 1.0

  // stage one 64-wide K tile + V^T tile (64 rows x 128B each)
  auto stageKV = [&](int b, int T) {
    const u16* Kt = Kh + (size_t)T * 64 * HD;
    const u16* Vs = Vh + (size_t)T * 64;
    char* Kb = lds + b * 8192;
    char* Vb = lds + 16384 + b * 8192;
#pragma unroll
    for (int i = 0; i < 2; i++) {
      int row = i * 32 + srow;
      int c = (sch ^ (row & 7)) << 3;
      gload_lds16(Kt + (size_t)row * HD + c, Kb + row * 128 + sch * 16);
      gload_lds16(Vs + (size_t)row * SEQ + c, Vb + row * 128 + sch * 16);
    }
  };

  int nT = qt + 1;                      // 64-wide kv tiles covering [0,(qt+1)*64)
  int qb = qt * 64 + sub * 32;

  bf16x8 qf[2][2];
#pragma unroll
  for (int mi = 0; mi < 2; mi++)
#pragma unroll
    for (int ks = 0; ks < 2; ks++)
      qf[mi][ks] = *reinterpret_cast<const bf16x8*>(
          Qh + (size_t)(qb + mi * 16 + l15) * HD + ks * 32 + l4 * 8);

  float mrun[2] = {-1e30f, -1e30f};
  f32x4 oacc[4][2] = {};
  f32x4 acc_l[2] = {};
  bf16x8 pf_c[2], vf_c[4];   // deferred-PV carry registers (16 + 32 VGPR)
  bool pend = false;

  int buf = 0;
  stageKV(0, 0);
  __syncthreads();   // tile 0 resident

  for (int T = 0; T < nT; T++) {
    if (T + 1 < nT) stageKV(buf ^ 1, T + 1);
    char* Kw = lds + buf * 8192;
    char* Vw = lds + 16384 + buf * 8192;
    int kvb = T * 64 + par * 32;

    __builtin_amdgcn_s_setprio(1);
    // deferred PV(T-1): pure-reg MFMAs, overlap with QK's ds_reads
    if (pend) {
#pragma unroll
      for (int nd = 0; nd < 4; nd++)
#pragma unroll
        for (int mi = 0; mi < 2; mi++)
          oacc[nd][mi] = __builtin_amdgcn_mfma_f32_16x16x32_bf16(
              vf_c[nd], pf_c[mi], oacc[nd][mi], 0, 0, 0);
#pragma unroll
      for (int mi = 0; mi < 2; mi++)
        acc_l[mi] = __builtin_amdgcn_mfma_f32_16x16x32_bf16(onesf, pf_c[mi], acc_l[mi], 0, 0, 0);
    }

    // S^T = K . Q^T  (D: row = kv = l4*4+r within nj tile, col = q = l15)
    f32x4 s[2][2] = {};
#pragma unroll
    for (int ks = 0; ks < 2; ks++)
#pragma unroll
      for (int nj = 0; nj < 2; nj++) {
        bf16x8 kf = *reinterpret_cast<const bf16x8*>(
            Kw + swz128(par * 32 + nj * 16 + l15, ks * 4 + l4));
#pragma unroll
        for (int mi = 0; mi < 2; mi++)
          s[nj][mi] = __builtin_amdgcn_mfma_f32_16x16x32_bf16(kf, qf[mi][ks], s[nj][mi], 0, 0, 0);
      }
    __builtin_amdgcn_s_setprio(0);

    // V fragments for THIS tile (consumed by next step's deferred PV)
#pragma unroll
    for (int nd = 0; nd < 4; nd++)
      vf_c[nd] = *reinterpret_cast<const bf16x8*>(
          Vw + swz128(nd * 16 + l15, par * 4 + l4));

    // causal mask: only tiles touching the diagonal
    if (kvb + 31 > qb) {
#pragma unroll
      for (int nj = 0; nj < 2; nj++)
#pragma unroll
        for (int mi = 0; mi < 2; mi++) {
          int qg = qb + mi * 16 + l15;
#pragma unroll
          for (int r = 0; r < 4; r++) {
            int kg = kvb + nj * 16 + l4 * 4 + r;
            if (kg > qg) s[nj][mi][r] = MVAL;
          }
        }
    }

    // tile row-max (q lane-local, reduce across l4: 2 shuffles)
    float mt[2];
#pragma unroll
    for (int mi = 0; mi < 2; mi++) {
      float m = s[0][mi][0];
#pragma unroll
      for (int nj = 0; nj < 2; nj++)
#pragma unroll
        for (int r = 0; r < 4; r++) m = fmaxf(m, s[nj][mi][r]);
      m = fmaxf(m, __shfl_xor(m, 16));
      m = fmaxf(m, __shfl_xor(m, 32));
      mt[mi] = m;
    }

    // defer-max: skip rescale when running max unchanged (exact, THR=0)
    if (!__all((mt[0] <= mrun[0]) & (mt[1] <= mrun[1]))) {
#pragma unroll
      for (int mi = 0; mi < 2; mi++) {
        float mnew = fmaxf(mrun[mi], mt[mi]);
        float alpha = EXP2(mrun[mi] - mnew);
        mrun[mi] = mnew;
#pragma unroll
        for (int nd = 0; nd < 4; nd++)
#pragma unroll
          for (int r = 0; r < 4; r++) oacc[nd][mi][r] *= alpha;
#pragma unroll
        for (int r = 0; r < 4; r++) acc_l[mi][r] *= alpha;
      }
    }

    // P = exp2(s - m) -> bf16 P in per-wave LDS (chunks 0..3, swizzled)
#pragma unroll
    for (int mi = 0; mi < 2; mi++) {
      int prow = mi * 16 + l15;
#pragma unroll
      for (int nj = 0; nj < 2; nj++) {
        float p0 = EXP2(s[nj][mi][0] - mrun[mi]);
        float p1 = EXP2(s[nj][mi][1] - mrun[mi]);
        float p2 = EXP2(s[nj][mi][2] - mrun[mi]);
        float p3 = EXP2(s[nj][mi][3] - mrun[mi]);
        int chunk = nj * 2 + (l4 >> 1);
        char* dst = Pw + prow * 128 + (((chunk ^ (prow & 7)) & 7) << 4) + (l4 & 1) * 8;
        *reinterpret_cast<uint2*>(dst) = make_uint2(pk2(p0, p1), pk2(p2, p3));
      }
    }

    asm volatile("s_waitcnt lgkmcnt(0)" ::: "memory");
    __builtin_amdgcn_sched_barrier(0);

    // P fragments into carry regs (consumed next step); chunk = l4
#pragma unroll
    for (int mi = 0; mi < 2; mi++)
      pf_c[mi] = *reinterpret_cast<const bf16x8*>(Pw + swz128(mi * 16 + l15, l4));
    pend = true;

    __syncthreads();  // drains vmcnt: tile T+1 resident
    buf ^= 1;
  }

  // flush last pending PV
  __builtin_amdgcn_s_setprio(1);
#pragma unroll
  for (int nd = 0; nd < 4; nd++)
#pragma unroll
    for (int mi = 0; mi < 2; mi++)
      oacc[nd][mi] = __builtin_amdgcn_mfma_f32_16x16x32_bf16(
          vf_c[nd], pf_c[mi], oacc[nd][mi], 0, 0, 0);
#pragma unroll
  for (int mi = 0; mi < 2; mi++)
    acc_l[mi] = __builtin_amdgcn_mfma_f32_16x16x32_bf16(onesf, pf_c[mi], acc_l[mi], 0, 0, 0);
  __builtin_amdgcn_s_setprio(0);

  // ---- cross-parity merge: Xo spans both (dead) K buffers, Xml in dead V ----
  char* Xo = lds;                       // 64 rows x 256B fp32
  float* Xml = (float*)(lds + 16384);   // 64 x (m,l)
  if (par == 1) {
#pragma unroll
    for (int mi = 0; mi < 2; mi++) {
      int row = sub * 32 + mi * 16 + l15;
      if (l4 == 0) {
        Xml[row * 2] = mrun[mi];
        Xml[row * 2 + 1] = acc_l[mi][0];
      }
#pragma unroll
      for (int nd = 0; nd < 4; nd++)
        *reinterpret_cast<f32x4*>(Xo + row * 256 + (((nd * 4 + l4) ^ (row & 7)) << 4)) =
            oacc[nd][mi];
    }
  }
  __syncthreads();
  if (par == 0) {
#pragma unroll
    for (int mi = 0; mi < 2; mi++) {
      int row = sub * 32 + mi * 16 + l15;
      float mB = Xml[row * 2], lB = Xml[row * 2 + 1];
      float m = fmaxf(mrun[mi], mB);
      float wA = EXP2(mrun[mi] - m), wB = EXP2(mB - m);
      float linv = 1.0f / (acc_l[mi][0] * wA + lB * wB);
      float fA = wA * linv, fB = wB * linv;
      u16* orow = O + ((size_t)b_ * SEQ + qt * 64 + sub * 32 + mi * 16 + l15) * DIM + h_ * HD;
#pragma unroll
      for (int nd = 0; nd < 4; nd++) {
        f32x4 ob = *reinterpret_cast<const f32x4*>(
            Xo + row * 256 + (((nd * 4 + l4) ^ (row & 7)) << 4));
        float o0 = oacc[nd][mi][0] * fA + ob[0] * fB;
        float o1 = oacc[nd][mi][1] * fA + ob[1] * fB;
        float o2 = oacc[nd][mi][2] * fA + ob[2] * fB;
        float o3 = oacc[nd][mi][3] * fA + ob[3] * fB;
        *reinterpret_cast<uint2*>(orow + nd * 16 + l4 * 4) = make_uint2(pk2(o0, o1), pk2(o2, o3));
      }
    }
  }
}

extern "C" void kernel_launch(void* const* d_in, const int* in_sizes, int n_in,
                              void* d_out, int out_size, void* d_ws, size_t ws_size,
                              hipStream_t stream) {
  const float* x     = (const float*)d_in[0];
  const float* W_qkv = (const float*)d_in[1];
  const float* b_qkv = (const float*)d_in[2];
  const float* W_out = (const float*)d_in[3];
  const float* b_out = (const float*)d_in[4];
  float* out = (float*)d_out;
  char* ws = (char*)d_ws;

  // ws layout (bytes)
  u16* xb    = (u16*)(ws);                               // 8 MB  [4096][1024]
  u16* WqkvT = (u16*)(ws + 8388608);                     // 6 MB  [3072][1024]
  u16* WoutT = (u16*)(ws + 8388608 + 6291456);           // 2 MB  [1024][1024]
  u16* Qb    = (u16*)(ws + 16777216);                    // 8 MB  [32][2048][64]
  u16* Kb    = (u16*)(ws + 16777216 + 8388608);          // 8 MB  [32][2048][64]
  u16* Vtb   = (u16*)(ws + 16777216 + 2 * 8388608);      // 8 MB  [32][64][2048]
  u16* Ob    = (u16*)(ws + 16777216 + 3 * 8388608);      // 8 MB  [4096][1024]

  prep_kernel<<<4096 + 3072 + 1024, 256, 0, stream>>>(x, xb, W_qkv, WqkvT, W_out, WoutT);
  gemm_bt_kernel<0><<<dim3(3 * DIM / 128, BATCH * SEQ / 128), 256, 0, stream>>>(
      xb, WqkvT, b_qkv, nullptr, Qb, Kb, Vtb, BATCH * SEQ, 3 * DIM, DIM);
  attn_kernel<<<1024, 256, 0, stream>>>(Qb, Kb, Vtb, Ob);
  gemm_bt_kernel<1><<<dim3(DIM / 128, BATCH * SEQ / 128), 256, 0, stream>>>(
      Ob, WoutT, b_out, out, nullptr, nullptr, nullptr, BATCH * SEQ, DIM, DIM);
}

// Round 20
// 106.471 us; speedup vs baseline: 1.0635x; 1.0410x over previous
//
#include <hip/hip_runtime.h>
#include <hip/hip_bf16.h>
#include <stdint.h>

#define BATCH 2
#define SEQ   2048
#define DIM   1024
#define NH    16
#define HD    64
#define MVAL  (-10000.0f)

// Native exp2 (raw v_exp_f32, no libm fixup). Fallback: e-domain with __expf.
#if __has_builtin(__builtin_amdgcn_exp2f)
#define EXP2(x) __builtin_amdgcn_exp2f(x)
#define QSCALE  (0.125f * 1.44269504f)   // fold softmax scale AND log2(e) into Q
#else
#define EXP2(x) __expf(x)
#define QSCALE  0.125f
#endif

typedef __attribute__((ext_vector_type(8))) short bf16x8;
typedef __attribute__((ext_vector_type(4))) float f32x4;
typedef unsigned short u16;

static __device__ __forceinline__ u16 f2bf(float f) {
  union { float f; uint32_t u; } c; c.f = f;
  uint32_t x = c.u;
  return (u16)((x + 0x7fffu + ((x >> 16) & 1u)) >> 16);  // RNE
}

static __device__ __forceinline__ uint32_t pk2(float a, float b) {
  __hip_bfloat162 h = __float22bfloat162_rn(make_float2(a, b));
  union { __hip_bfloat162 h; uint32_t u; } c; c.h = h;
  return c.u;
}

// swizzled byte offset within LDS tiles of 128B rows (8 x 16B chunks)
static __device__ __forceinline__ int swz128(int row, int chunk) {
  return row * 128 + (((chunk ^ (row & 7)) & 7) << 4);
}

static __device__ __forceinline__ void gload_lds16(const void* g, void* l) {
  __builtin_amdgcn_global_load_lds((const __attribute__((address_space(1))) void*)g,
                                   (__attribute__((address_space(3))) void*)l, 16, 0, 0);
}

// -------- fused prep: fp32->bf16 convert of x + both weight transposes --------
__global__ void prep_kernel(const float* __restrict__ x, u16* __restrict__ xb,
                            const float* __restrict__ Wqkv, u16* __restrict__ WqkvT,
                            const float* __restrict__ Wout, u16* __restrict__ WoutT) {
  __shared__ float tile[32][33];
  int blk = blockIdx.x, tid = threadIdx.x;
  if (blk < 4096) {
    int i = blk * 256 + tid;
    float4 v = reinterpret_cast<const float4*>(x)[i];
    reinterpret_cast<uint2*>(xb)[i] = make_uint2(pk2(v.x, v.y), pk2(v.z, v.w));
    return;
  }
  const float* in;
  u16* out;
  int C, t;
  if (blk < 4096 + 3072) { t = blk - 4096; in = Wqkv; out = WqkvT; C = 3072; }
  else                   { t = blk - 7168; in = Wout; out = WoutT; C = 1024; }
  int R = DIM;
  int c0 = (t % (C / 32)) * 32, r0 = (t / (C / 32)) * 32;
  int tx = tid & 31, ty = tid >> 5;
#pragma unroll
  for (int i = 0; i < 32; i += 8)
    tile[ty + i][tx] = in[(size_t)(r0 + ty + i) * C + c0 + tx];
  __syncthreads();
#pragma unroll
  for (int i = 0; i < 32; i += 8)
    out[(size_t)(c0 + ty + i) * R + r0 + tx] = f2bf(tile[tx][ty + i]);
}

// ---------------- bf16 GEMM: C = A[M,128/BN tile] x Bt + bias ----------------
// Tile = 128 x BN (BN in {128,64}); 4 waves (wr x wc = 2x2), per-wave 64 x BN/2.
// Swizzled LDS (pre-swizzled gload_lds source + swizzled ds_read_b128).
// SWAPPED mfma operands: lane's acc quad holds 4 consecutive n -> packed stores.
// EPI==0 (BN=128): Q (x QSCALE) / K head-split [bh][s][d]; V transposed [bh][d][s].
// EPI==1: plain fp32 [M][N], 16B stores.
template <int EPI, int BN>
__global__ __launch_bounds__(256, 2) void gemm_bt_kernel(
    const u16* __restrict__ A, const u16* __restrict__ Bt,
    const float* __restrict__ bias, float* __restrict__ Cout,
    u16* __restrict__ Qo, u16* __restrict__ Ko, u16* __restrict__ Vto,
    int M, int N, int K) {
  constexpr int NF = BN / 32;              // n-frags per wave
  __shared__ __align__(16) char lds[16384 + BN * 128];
  char* As = lds;            // 128 rows x 64 bf16, swizzled
  char* Bs = lds + 16384;    // BN rows x 64 bf16, swizzled
  int tid = threadIdx.x;
  int lane = tid & 63, l15 = lane & 15, l4 = lane >> 4;
  int w = tid >> 6, wr = w >> 1, wc = w & 1;
  int m0 = blockIdx.y * 128, n0 = blockIdx.x * BN;
  int srow = tid >> 3, sch = tid & 7;
  int sc_swz = ((sch ^ (srow & 7)) << 3);  // pre-swizzled source chunk (u16 units)

  const u16* Ap = A + (size_t)(m0 + srow) * K + sc_swz;
  const u16* Bp = Bt + (size_t)(n0 + srow) * K + sc_swz;

  f32x4 acc[NF][4] = {};  // acc[nj][mi]: quad holds 4 consecutive n

  for (int k0 = 0; k0 < K; k0 += 64) {
    __syncthreads();
#pragma unroll
    for (int i = 0; i < 4; i++)
      gload_lds16(Ap + (size_t)i * 32 * K + k0, As + i * 4096 + tid * 16);
#pragma unroll
    for (int i = 0; i < BN / 32; i++)
      gload_lds16(Bp + (size_t)i * 32 * K + k0, Bs + i * 4096 + tid * 16);
    __syncthreads();
#pragma unroll
    for (int ks = 0; ks < 2; ks++) {
      int ch = ks * 4 + l4;
      bf16x8 af[4], bfv[NF];
#pragma unroll
      for (int mi = 0; mi < 4; mi++)
        af[mi] = *reinterpret_cast<const bf16x8*>(As + swz128(wr * 64 + mi * 16 + l15, ch));
#pragma unroll
      for (int nj = 0; nj < NF; nj++)
        bfv[nj] = *reinterpret_cast<const bf16x8*>(Bs + swz128(wc * (BN / 2) + nj * 16 + l15, ch));
#pragma unroll
      for (int nj = 0; nj < NF; nj++)
#pragma unroll
        for (int mi = 0; mi < 4; mi++)
          acc[nj][mi] = __builtin_amdgcn_mfma_f32_16x16x32_bf16(bfv[nj], af[mi], acc[nj][mi], 0, 0, 0);
    }
  }

  // epilogue: lane holds C[m][nb..nb+3], m = ..+l15, nb = ..+l4*4
#pragma unroll
  for (int nj = 0; nj < NF; nj++) {
    int nb = n0 + wc * (BN / 2) + nj * 16 + l4 * 4;
    float4 bv = *reinterpret_cast<const float4*>(bias + nb);
#pragma unroll
    for (int mi = 0; mi < 4; mi++) {
      int m = m0 + wr * 64 + mi * 16 + l15;
      f32x4 a = acc[nj][mi];
      float v0 = a[0] + bv.x, v1 = a[1] + bv.y, v2 = a[2] + bv.z, v3 = a[3] + bv.w;
      if (EPI == 1) {
        *reinterpret_cast<float4*>(Cout + (size_t)m * N + nb) = make_float4(v0, v1, v2, v3);
      } else {
        int b = m >> 11, s = m & 2047;
        int sec = nb >> 10, c = nb & 1023, h = c >> 6, d = c & 63;  // sec,h wave-uniform
        size_t bh = (size_t)(b * NH + h);
        if (sec == 0) {
          *reinterpret_cast<uint2*>(Qo + (bh * SEQ + s) * HD + d) =
              make_uint2(pk2(v0 * QSCALE, v1 * QSCALE), pk2(v2 * QSCALE, v3 * QSCALE));
        } else if (sec == 1) {
          *reinterpret_cast<uint2*>(Ko + (bh * SEQ + s) * HD + d) =
              make_uint2(pk2(v0, v1), pk2(v2, v3));
        } else {
          // V transposed: [bh][d][s]; lanes (l15 = s) make 32B contiguous runs
          u16* vt = Vto + (bh * HD + d) * SEQ + s;
          vt[0]       = f2bf(v0);
          vt[SEQ]     = f2bf(v1);
          vt[2 * SEQ] = f2bf(v2);
          vt[3 * SEQ] = f2bf(v3);
        }
      }
    }
  }
}

// ------- causal flash attention: 64-wide KV tiles, 3 blocks/CU + deferred PV -------
// 1024 blocks x 256 thr, 48KB LDS. qt via constant-sum zigzag: each CU's four
// block-slots (g fixed, k=0..3) sum to 62 step-slots; heavy tiles dispatch first.
// Wave = sub (q 32-half) x par (kv 32-half). Double-buffered gload_lds staging,
// 1 barrier/step. Deferred PV carried in regs across the barrier (r10-verified
// exact reordering). Parity merge through dead K/V regions.
__global__ __launch_bounds__(256, 3) void attn_kernel(
    const u16* __restrict__ Q, const u16* __restrict__ K,
    const u16* __restrict__ Vt, u16* __restrict__ O) {
  __shared__ __align__(16) char lds[49152];  // K 2x8K | V 2x8K | P 4x4K
  int tid = threadIdx.x, lane = tid & 63, w = tid >> 6;
  int l15 = lane & 15, l4 = lane >> 4;
  int sub = w & 1, par = w >> 1;
  int blk = blockIdx.x;
  int bh = (blk & 7) * 4 + ((blk >> 3) & 3);   // XCD-clustered
  int g = (blk >> 5) & 7, k = blk >> 8;
  int qt = ((3 - k) << 3) | ((k & 1) ? (7 - g) : g);  // constant per-CU sum, heavy first
  const u16* Qh = Q + (size_t)bh * SEQ * HD;
  const u16* Kh = K + (size_t)bh * SEQ * HD;
  const u16* Vh = Vt + (size_t)bh * HD * SEQ;
  char* Pw = lds + 32768 + w * 4096;
  int srow = tid >> 3, sch = tid & 7;
  int b_ = bh >> 4, h_ = bh & 15;

  bf16x8 onesf;
#pragma unroll
  for (int j = 0; j < 8; j++) onesf[j] = (short)0x3F80;  // bf16 1.0

  // stage one 64-wide K tile + V^T tile (64 rows x 128B each)
  auto stageKV = [&](int b, int T) {
    const u16* Kt = Kh + (size_t)T * 64 * HD;
    const u16* Vs = Vh + (size_t)T * 64;
    char* Kb = lds + b * 8192;
    char* Vb = lds + 16384 + b * 8192;
#pragma unroll
    for (int i = 0; i < 2; i++) {
      int row = i * 32 + srow;
      int c = (sch ^ (row & 7)) << 3;
      gload_lds16(Kt + (size_t)row * HD + c, Kb + row * 128 + sch * 16);
      gload_lds16(Vs + (size_t)row * SEQ + c, Vb + row * 128 + sch * 16);
    }
  };

  int nT = qt + 1;                      // 64-wide kv tiles covering [0,(qt+1)*64)
  int qb = qt * 64 + sub * 32;

  bf16x8 qf[2][2];
#pragma unroll
  for (int mi = 0; mi < 2; mi++)
#pragma unroll
    for (int ks = 0; ks < 2; ks++)
      qf[mi][ks] = *reinterpret_cast<const bf16x8*>(
          Qh + (size_t)(qb + mi * 16 + l15) * HD + ks * 32 + l4 * 8);

  float mrun[2] = {-1e30f, -1e30f};
  f32x4 oacc[4][2] = {};
  f32x4 acc_l[2] = {};
  bf16x8 pf_c[2], vf_c[4];   // deferred-PV carry registers
  bool pend = false;

  int buf = 0;
  stageKV(0, 0);
  __syncthreads();   // tile 0 resident

  for (int T = 0; T < nT; T++) {
    if (T + 1 < nT) stageKV(buf ^ 1, T + 1);
    char* Kw = lds + buf * 8192;
    char* Vw = lds + 16384 + buf * 8192;
    int kvb = T * 64 + par * 32;

    __builtin_amdgcn_s_setprio(1);
    // deferred PV(T-1): pure-reg MFMAs, overlap with QK's ds_reads
    if (pend) {
#pragma unroll
      for (int nd = 0; nd < 4; nd++)
#pragma unroll
        for (int mi = 0; mi < 2; mi++)
          oacc[nd][mi] = __builtin_amdgcn_mfma_f32_16x16x32_bf16(
              vf_c[nd], pf_c[mi], oacc[nd][mi], 0, 0, 0);
#pragma unroll
      for (int mi = 0; mi < 2; mi++)
        acc_l[mi] = __builtin_amdgcn_mfma_f32_16x16x32_bf16(onesf, pf_c[mi], acc_l[mi], 0, 0, 0);
    }

    // S^T = K . Q^T  (D: row = kv = l4*4+r within nj tile, col = q = l15)
    f32x4 s[2][2] = {};
#pragma unroll
    for (int ks = 0; ks < 2; ks++)
#pragma unroll
      for (int nj = 0; nj < 2; nj++) {
        bf16x8 kf = *reinterpret_cast<const bf16x8*>(
            Kw + swz128(par * 32 + nj * 16 + l15, ks * 4 + l4));
#pragma unroll
        for (int mi = 0; mi < 2; mi++)
          s[nj][mi] = __builtin_amdgcn_mfma_f32_16x16x32_bf16(kf, qf[mi][ks], s[nj][mi], 0, 0, 0);
      }
    __builtin_amdgcn_s_setprio(0);

    // V fragments for THIS tile (consumed by next step's deferred PV)
#pragma unroll
    for (int nd = 0; nd < 4; nd++)
      vf_c[nd] = *reinterpret_cast<const bf16x8*>(
          Vw + swz128(nd * 16 + l15, par * 4 + l4));

    // causal mask: only tiles touching the diagonal
    if (kvb + 31 > qb) {
#pragma unroll
      for (int nj = 0; nj < 2; nj++)
#pragma unroll
        for (int mi = 0; mi < 2; mi++) {
          int qg = qb + mi * 16 + l15;
#pragma unroll
          for (int r = 0; r < 4; r++) {
            int kg = kvb + nj * 16 + l4 * 4 + r;
            if (kg > qg) s[nj][mi][r] = MVAL;
          }
        }
    }

    // tile row-max (q lane-local, reduce across l4: 2 shuffles)
    float mt[2];
#pragma unroll
    for (int mi = 0; mi < 2; mi++) {
      float m = s[0][mi][0];
#pragma unroll
      for (int nj = 0; nj < 2; nj++)
#pragma unroll
        for (int r = 0; r < 4; r++) m = fmaxf(m, s[nj][mi][r]);
      m = fmaxf(m, __shfl_xor(m, 16));
      m = fmaxf(m, __shfl_xor(m, 32));
      mt[mi] = m;
    }

    // defer-max: skip rescale when running max unchanged (exact, THR=0)
    if (!__all((mt[0] <= mrun[0]) & (mt[1] <= mrun[1]))) {
#pragma unroll
      for (int mi = 0; mi < 2; mi++) {
        float mnew = fmaxf(mrun[mi], mt[mi]);
        float alpha = EXP2(mrun[mi] - mnew);
        mrun[mi] = mnew;
#pragma unroll
        for (int nd = 0; nd < 4; nd++)
#pragma unroll
          for (int r = 0; r < 4; r++) oacc[nd][mi][r] *= alpha;
#pragma unroll
        for (int r = 0; r < 4; r++) acc_l[mi][r] *= alpha;
      }
    }

    // P = exp2(s - m) -> bf16 P in per-wave LDS (chunks 0..3, swizzled)
#pragma unroll
    for (int mi = 0; mi < 2; mi++) {
      int prow = mi * 16 + l15;
#pragma unroll
      for (int nj = 0; nj < 2; nj++) {
        float p0 = EXP2(s[nj][mi][0] - mrun[mi]);
        float p1 = EXP2(s[nj][mi][1] - mrun[mi]);
        float p2 = EXP2(s[nj][mi][2] - mrun[mi]);
        float p3 = EXP2(s[nj][mi][3] - mrun[mi]);
        int chunk = nj * 2 + (l4 >> 1);
        char* dst = Pw + prow * 128 + (((chunk ^ (prow & 7)) & 7) << 4) + (l4 & 1) * 8;
        *reinterpret_cast<uint2*>(dst) = make_uint2(pk2(p0, p1), pk2(p2, p3));
      }
    }

    asm volatile("s_waitcnt lgkmcnt(0)" ::: "memory");
    __builtin_amdgcn_sched_barrier(0);

    // P fragments into carry regs (consumed next step); chunk = l4
#pragma unroll
    for (int mi = 0; mi < 2; mi++)
      pf_c[mi] = *reinterpret_cast<const bf16x8*>(Pw + swz128(mi * 16 + l15, l4));
    pend = true;

    __syncthreads();  // drains vmcnt: tile T+1 resident
    buf ^= 1;
  }

  // flush last pending PV
  __builtin_amdgcn_s_setprio(1);
#pragma unroll
  for (int nd = 0; nd < 4; nd++)
#pragma unroll
    for (int mi = 0; mi < 2; mi++)
      oacc[nd][mi] = __builtin_amdgcn_mfma_f32_16x16x32_bf16(
          vf_c[nd], pf_c[mi], oacc[nd][mi], 0, 0, 0);
#pragma unroll
  for (int mi = 0; mi < 2; mi++)
    acc_l[mi] = __builtin_amdgcn_mfma_f32_16x16x32_bf16(onesf, pf_c[mi], acc_l[mi], 0, 0, 0);
  __builtin_amdgcn_s_setprio(0);

  // ---- cross-parity merge: Xo spans both (dead) K buffers, Xml in dead V ----
  char* Xo = lds;                       // 64 rows x 256B fp32
  float* Xml = (float*)(lds + 16384);   // 64 x (m,l)
  if (par == 1) {
#pragma unroll
    for (int mi = 0; mi < 2; mi++) {
      int row = sub * 32 + mi * 16 + l15;
      if (l4 == 0) {
        Xml[row * 2] = mrun[mi];
        Xml[row * 2 + 1] = acc_l[mi][0];
      }
#pragma unroll
      for (int nd = 0; nd < 4; nd++)
        *reinterpret_cast<f32x4*>(Xo + row * 256 + (((nd * 4 + l4) ^ (row & 7)) << 4)) =
            oacc[nd][mi];
    }
  }
  __syncthreads();
  if (par == 0) {
#pragma unroll
    for (int mi = 0; mi < 2; mi++) {
      int row = sub * 32 + mi * 16 + l15;
      float mB = Xml[row * 2], lB = Xml[row * 2 + 1];
      float m = fmaxf(mrun[mi], mB);
      float wA = EXP2(mrun[mi] - m), wB = EXP2(mB - m);
      float linv = 1.0f / (acc_l[mi][0] * wA + lB * wB);
      float fA = wA * linv, fB = wB * linv;
      u16* orow = O + ((size_t)b_ * SEQ + qt * 64 + sub * 32 + mi * 16 + l15) * DIM + h_ * HD;
#pragma unroll
      for (int nd = 0; nd < 4; nd++) {
        f32x4 ob = *reinterpret_cast<const f32x4*>(
            Xo + row * 256 + (((nd * 4 + l4) ^ (row & 7)) << 4));
        float o0 = oacc[nd][mi][0] * fA + ob[0] * fB;
        float o1 = oacc[nd][mi][1] * fA + ob[1] * fB;
        float o2 = oacc[nd][mi][2] * fA + ob[2] * fB;
        float o3 = oacc[nd][mi][3] * fA + ob[3] * fB;
        *reinterpret_cast<uint2*>(orow + nd * 16 + l4 * 4) = make_uint2(pk2(o0, o1), pk2(o2, o3));
      }
    }
  }
}

extern "C" void kernel_launch(void* const* d_in, const int* in_sizes, int n_in,
                              void* d_out, int out_size, void* d_ws, size_t ws_size,
                              hipStream_t stream) {
  const float* x     = (const float*)d_in[0];
  const float* W_qkv = (const float*)d_in[1];
  const float* b_qkv = (const float*)d_in[2];
  const float* W_out = (const float*)d_in[3];
  const float* b_out = (const float*)d_in[4];
  float* out = (float*)d_out;
  char* ws = (char*)d_ws;

  // ws layout (bytes)
  u16* xb    = (u16*)(ws);                               // 8 MB  [4096][1024]
  u16* WqkvT = (u16*)(ws + 8388608);                     // 6 MB  [3072][1024]
  u16* WoutT = (u16*)(ws + 8388608 + 6291456);           // 2 MB  [1024][1024]
  u16* Qb    = (u16*)(ws + 16777216);                    // 8 MB  [32][2048][64]
  u16* Kb    = (u16*)(ws + 16777216 + 8388608);          // 8 MB  [32][2048][64]
  u16* Vtb   = (u16*)(ws + 16777216 + 2 * 8388608);      // 8 MB  [32][64][2048]
  u16* Ob    = (u16*)(ws + 16777216 + 3 * 8388608);      // 8 MB  [4096][1024]

  prep_kernel<<<4096 + 3072 + 1024, 256, 0, stream>>>(x, xb, W_qkv, WqkvT, W_out, WoutT);
  gemm_bt_kernel<0, 128><<<dim3(3 * DIM / 128, BATCH * SEQ / 128), 256, 0, stream>>>(
      xb, WqkvT, b_qkv, nullptr, Qb, Kb, Vtb, BATCH * SEQ, 3 * DIM, DIM);
  attn_kernel<<<1024, 256, 0, stream>>>(Qb, Kb, Vtb, Ob);
  gemm_bt_kernel<1, 64><<<dim3(DIM / 64, BATCH * SEQ / 128), 256, 0, stream>>>(
      Ob, WoutT, b_out, out, nullptr, nullptr, nullptr, BATCH * SEQ, DIM, DIM);
}

// Round 21
// 105.899 us; speedup vs baseline: 1.0692x; 1.0054x over previous
//
#include <hip/hip_runtime.h>
#include <hip/hip_bf16.h>
#include <stdint.h>

#define BATCH 2
#define SEQ   2048
#define DIM   1024
#define NH    16
#define HD    64
#define MVAL  (-10000.0f)

// Native exp2 (raw v_exp_f32, no libm fixup). Fallback: e-domain with __expf.
#if __has_builtin(__builtin_amdgcn_exp2f)
#define EXP2(x) __builtin_amdgcn_exp2f(x)
#define QSCALE  (0.125f * 1.44269504f)   // fold softmax scale AND log2(e) into Q
#else
#define EXP2(x) __expf(x)
#define QSCALE  0.125f
#endif

typedef __attribute__((ext_vector_type(8))) short bf16x8;
typedef __attribute__((ext_vector_type(4))) float f32x4;
typedef unsigned short u16;

static __device__ __forceinline__ u16 f2bf(float f) {
  union { float f; uint32_t u; } c; c.f = f;
  uint32_t x = c.u;
  return (u16)((x + 0x7fffu + ((x >> 16) & 1u)) >> 16);  // RNE
}

static __device__ __forceinline__ uint32_t pk2(float a, float b) {
  __hip_bfloat162 h = __float22bfloat162_rn(make_float2(a, b));
  union { __hip_bfloat162 h; uint32_t u; } c; c.h = h;
  return c.u;
}

// swizzled byte offset within LDS tiles of 128B rows (8 x 16B chunks)
static __device__ __forceinline__ int swz128(int row, int chunk) {
  return row * 128 + (((chunk ^ (row & 7)) & 7) << 4);
}

static __device__ __forceinline__ void gload_lds16(const void* g, void* l) {
  __builtin_amdgcn_global_load_lds((const __attribute__((address_space(1))) void*)g,
                                   (__attribute__((address_space(3))) void*)l, 16, 0, 0);
}

// -------- fused prep: fp32->bf16 convert of x + both weight transposes --------
__global__ void prep_kernel(const float* __restrict__ x, u16* __restrict__ xb,
                            const float* __restrict__ Wqkv, u16* __restrict__ WqkvT,
                            const float* __restrict__ Wout, u16* __restrict__ WoutT) {
  __shared__ float tile[32][33];
  int blk = blockIdx.x, tid = threadIdx.x;
  if (blk < 4096) {
    int i = blk * 256 + tid;
    float4 v = reinterpret_cast<const float4*>(x)[i];
    reinterpret_cast<uint2*>(xb)[i] = make_uint2(pk2(v.x, v.y), pk2(v.z, v.w));
    return;
  }
  const float* in;
  u16* out;
  int C, t;
  if (blk < 4096 + 3072) { t = blk - 4096; in = Wqkv; out = WqkvT; C = 3072; }
  else                   { t = blk - 7168; in = Wout; out = WoutT; C = 1024; }
  int R = DIM;
  int c0 = (t % (C / 32)) * 32, r0 = (t / (C / 32)) * 32;
  int tx = tid & 31, ty = tid >> 5;
#pragma unroll
  for (int i = 0; i < 32; i += 8)
    tile[ty + i][tx] = in[(size_t)(r0 + ty + i) * C + c0 + tx];
  __syncthreads();
#pragma unroll
  for (int i = 0; i < 32; i += 8)
    out[(size_t)(c0 + ty + i) * R + r0 + tx] = f2bf(tile[tx][ty + i]);
}

// ---------------- bf16 GEMM: C = A[M,128/BN tile] x Bt + bias ----------------
// Tile = 128 x BN (BN in {128,64}); 4 waves (wr x wc = 2x2), per-wave 64 x BN/2.
// Swizzled LDS (pre-swizzled gload_lds source + swizzled ds_read_b128).
// SWAPPED mfma operands: lane's acc quad holds 4 consecutive n -> packed stores.
// EPI==0 (BN=128): Q (x QSCALE) / K head-split [bh][s][d]; V transposed [bh][d][s].
// EPI==1: plain fp32 [M][N], 16B stores.
template <int EPI, int BN>
__global__ __launch_bounds__(256, 2) void gemm_bt_kernel(
    const u16* __restrict__ A, const u16* __restrict__ Bt,
    const float* __restrict__ bias, float* __restrict__ Cout,
    u16* __restrict__ Qo, u16* __restrict__ Ko, u16* __restrict__ Vto,
    int M, int N, int K) {
  constexpr int NF = BN / 32;              // n-frags per wave
  __shared__ __align__(16) char lds[16384 + BN * 128];
  char* As = lds;            // 128 rows x 64 bf16, swizzled
  char* Bs = lds + 16384;    // BN rows x 64 bf16, swizzled
  int tid = threadIdx.x;
  int lane = tid & 63, l15 = lane & 15, l4 = lane >> 4;
  int w = tid >> 6, wr = w >> 1, wc = w & 1;
  int m0 = blockIdx.y * 128, n0 = blockIdx.x * BN;
  int srow = tid >> 3, sch = tid & 7;
  int sc_swz = ((sch ^ (srow & 7)) << 3);  // pre-swizzled source chunk (u16 units)

  const u16* Ap = A + (size_t)(m0 + srow) * K + sc_swz;
  const u16* Bp = Bt + (size_t)(n0 + srow) * K + sc_swz;

  f32x4 acc[NF][4] = {};  // acc[nj][mi]: quad holds 4 consecutive n

  for (int k0 = 0; k0 < K; k0 += 64) {
    __syncthreads();
#pragma unroll
    for (int i = 0; i < 4; i++)
      gload_lds16(Ap + (size_t)i * 32 * K + k0, As + i * 4096 + tid * 16);
#pragma unroll
    for (int i = 0; i < BN / 32; i++)
      gload_lds16(Bp + (size_t)i * 32 * K + k0, Bs + i * 4096 + tid * 16);
    __syncthreads();
#pragma unroll
    for (int ks = 0; ks < 2; ks++) {
      int ch = ks * 4 + l4;
      bf16x8 af[4], bfv[NF];
#pragma unroll
      for (int mi = 0; mi < 4; mi++)
        af[mi] = *reinterpret_cast<const bf16x8*>(As + swz128(wr * 64 + mi * 16 + l15, ch));
#pragma unroll
      for (int nj = 0; nj < NF; nj++)
        bfv[nj] = *reinterpret_cast<const bf16x8*>(Bs + swz128(wc * (BN / 2) + nj * 16 + l15, ch));
#pragma unroll
      for (int nj = 0; nj < NF; nj++)
#pragma unroll
        for (int mi = 0; mi < 4; mi++)
          acc[nj][mi] = __builtin_amdgcn_mfma_f32_16x16x32_bf16(bfv[nj], af[mi], acc[nj][mi], 0, 0, 0);
    }
  }

  // epilogue: lane holds C[m][nb..nb+3], m = ..+l15, nb = ..+l4*4
#pragma unroll
  for (int nj = 0; nj < NF; nj++) {
    int nb = n0 + wc * (BN / 2) + nj * 16 + l4 * 4;
    float4 bv = *reinterpret_cast<const float4*>(bias + nb);
#pragma unroll
    for (int mi = 0; mi < 4; mi++) {
      int m = m0 + wr * 64 + mi * 16 + l15;
      f32x4 a = acc[nj][mi];
      float v0 = a[0] + bv.x, v1 = a[1] + bv.y, v2 = a[2] + bv.z, v3 = a[3] + bv.w;
      if (EPI == 1) {
        *reinterpret_cast<float4*>(Cout + (size_t)m * N + nb) = make_float4(v0, v1, v2, v3);
      } else {
        int b = m >> 11, s = m & 2047;
        int sec = nb >> 10, c = nb & 1023, h = c >> 6, d = c & 63;  // sec,h wave-uniform
        size_t bh = (size_t)(b * NH + h);
        if (sec == 0) {
          *reinterpret_cast<uint2*>(Qo + (bh * SEQ + s) * HD + d) =
              make_uint2(pk2(v0 * QSCALE, v1 * QSCALE), pk2(v2 * QSCALE, v3 * QSCALE));
        } else if (sec == 1) {
          *reinterpret_cast<uint2*>(Ko + (bh * SEQ + s) * HD + d) =
              make_uint2(pk2(v0, v1), pk2(v2, v3));
        } else {
          // V transposed: [bh][d][s]; lanes (l15 = s) make 32B contiguous runs
          u16* vt = Vto + (bh * HD + d) * SEQ + s;
          vt[0]       = f2bf(v0);
          vt[SEQ]     = f2bf(v1);
          vt[2 * SEQ] = f2bf(v2);
          vt[3 * SEQ] = f2bf(v3);
        }
      }
    }
  }
}

// ------- causal flash attention: 64-wide KV tiles, 3 blocks/CU + deferred PV -------
// 1024 blocks x 256 thr, 48KB LDS, heavy-first qt (r19-verified best). Wave =
// sub (q 32-half) x par (kv 32-half). Double-buffered gload_lds staging, 1
// barrier/step. Deferred PV carried in regs across the barrier (exact
// reordering). Parity merge through dead K/V regions.
__global__ __launch_bounds__(256, 3) void attn_kernel(
    const u16* __restrict__ Q, const u16* __restrict__ K,
    const u16* __restrict__ Vt, u16* __restrict__ O) {
  __shared__ __align__(16) char lds[49152];  // K 2x8K | V 2x8K | P 4x4K
  int tid = threadIdx.x, lane = tid & 63, w = tid >> 6;
  int l15 = lane & 15, l4 = lane >> 4;
  int sub = w & 1, par = w >> 1;
  int blk = blockIdx.x;
  int bh = (blk & 7) * 4 + ((blk >> 3) & 3);   // XCD-clustered
  int qt = 31 - (blk >> 5);                    // heavy tiles dispatch first
  const u16* Qh = Q + (size_t)bh * SEQ * HD;
  const u16* Kh = K + (size_t)bh * SEQ * HD;
  const u16* Vh = Vt + (size_t)bh * HD * SEQ;
  char* Pw = lds + 32768 + w * 4096;
  int srow = tid >> 3, sch = tid & 7;
  int b_ = bh >> 4, h_ = bh & 15;

  bf16x8 onesf;
#pragma unroll
  for (int j = 0; j < 8; j++) onesf[j] = (short)0x3F80;  // bf16 1.0

  // stage one 64-wide K tile + V^T tile (64 rows x 128B each)
  auto stageKV = [&](int b, int T) {
    const u16* Kt = Kh + (size_t)T * 64 * HD;
    const u16* Vs = Vh + (size_t)T * 64;
    char* Kb = lds + b * 8192;
    char* Vb = lds + 16384 + b * 8192;
#pragma unroll
    for (int i = 0; i < 2; i++) {
      int row = i * 32 + srow;
      int c = (sch ^ (row & 7)) << 3;
      gload_lds16(Kt + (size_t)row * HD + c, Kb + row * 128 + sch * 16);
      gload_lds16(Vs + (size_t)row * SEQ + c, Vb + row * 128 + sch * 16);
    }
  };

  int nT = qt + 1;                      // 64-wide kv tiles covering [0,(qt+1)*64)
  int qb = qt * 64 + sub * 32;

  bf16x8 qf[2][2];
#pragma unroll
  for (int mi = 0; mi < 2; mi++)
#pragma unroll
    for (int ks = 0; ks < 2; ks++)
      qf[mi][ks] = *reinterpret_cast<const bf16x8*>(
          Qh + (size_t)(qb + mi * 16 + l15) * HD + ks * 32 + l4 * 8);

  float mrun[2] = {-1e30f, -1e30f};
  f32x4 oacc[4][2] = {};
  f32x4 acc_l[2] = {};
  bf16x8 pf_c[2], vf_c[4];   // deferred-PV carry registers
  bool pend = false;

  int buf = 0;
  stageKV(0, 0);
  __syncthreads();   // tile 0 resident

  for (int T = 0; T < nT; T++) {
    if (T + 1 < nT) stageKV(buf ^ 1, T + 1);
    char* Kw = lds + buf * 8192;
    char* Vw = lds + 16384 + buf * 8192;
    int kvb = T * 64 + par * 32;

    __builtin_amdgcn_s_setprio(1);
    // deferred PV(T-1): pure-reg MFMAs, overlap with QK's ds_reads
    if (pend) {
#pragma unroll
      for (int nd = 0; nd < 4; nd++)
#pragma unroll
        for (int mi = 0; mi < 2; mi++)
          oacc[nd][mi] = __builtin_amdgcn_mfma_f32_16x16x32_bf16(
              vf_c[nd], pf_c[mi], oacc[nd][mi], 0, 0, 0);
#pragma unroll
      for (int mi = 0; mi < 2; mi++)
        acc_l[mi] = __builtin_amdgcn_mfma_f32_16x16x32_bf16(onesf, pf_c[mi], acc_l[mi], 0, 0, 0);
    }

    // S^T = K . Q^T  (D: row = kv = l4*4+r within nj tile, col = q = l15)
    f32x4 s[2][2] = {};
#pragma unroll
    for (int ks = 0; ks < 2; ks++)
#pragma unroll
      for (int nj = 0; nj < 2; nj++) {
        bf16x8 kf = *reinterpret_cast<const bf16x8*>(
            Kw + swz128(par * 32 + nj * 16 + l15, ks * 4 + l4));
#pragma unroll
        for (int mi = 0; mi < 2; mi++)
          s[nj][mi] = __builtin_amdgcn_mfma_f32_16x16x32_bf16(kf, qf[mi][ks], s[nj][mi], 0, 0, 0);
      }
    __builtin_amdgcn_s_setprio(0);

    // V fragments for THIS tile (consumed by next step's deferred PV)
#pragma unroll
    for (int nd = 0; nd < 4; nd++)
      vf_c[nd] = *reinterpret_cast<const bf16x8*>(
          Vw + swz128(nd * 16 + l15, par * 4 + l4));

    // causal mask: only tiles touching the diagonal
    if (kvb + 31 > qb) {
#pragma unroll
      for (int nj = 0; nj < 2; nj++)
#pragma unroll
        for (int mi = 0; mi < 2; mi++) {
          int qg = qb + mi * 16 + l15;
#pragma unroll
          for (int r = 0; r < 4; r++) {
            int kg = kvb + nj * 16 + l4 * 4 + r;
            if (kg > qg) s[nj][mi][r] = MVAL;
          }
        }
    }

    // tile row-max (q lane-local, reduce across l4: 2 shuffles)
    float mt[2];
#pragma unroll
    for (int mi = 0; mi < 2; mi++) {
      float m = s[0][mi][0];
#pragma unroll
      for (int nj = 0; nj < 2; nj++)
#pragma unroll
        for (int r = 0; r < 4; r++) m = fmaxf(m, s[nj][mi][r]);
      m = fmaxf(m, __shfl_xor(m, 16));
      m = fmaxf(m, __shfl_xor(m, 32));
      mt[mi] = m;
    }

    // defer-max: skip rescale when running max unchanged (exact, THR=0)
    if (!__all((mt[0] <= mrun[0]) & (mt[1] <= mrun[1]))) {
#pragma unroll
      for (int mi = 0; mi < 2; mi++) {
        float mnew = fmaxf(mrun[mi], mt[mi]);
        float alpha = EXP2(mrun[mi] - mnew);
        mrun[mi] = mnew;
#pragma unroll
        for (int nd = 0; nd < 4; nd++)
#pragma unroll
          for (int r = 0; r < 4; r++) oacc[nd][mi][r] *= alpha;
#pragma unroll
        for (int r = 0; r < 4; r++) acc_l[mi][r] *= alpha;
      }
    }

    // P = exp2(s - m) -> bf16 P in per-wave LDS (chunks 0..3, swizzled)
#pragma unroll
    for (int mi = 0; mi < 2; mi++) {
      int prow = mi * 16 + l15;
#pragma unroll
      for (int nj = 0; nj < 2; nj++) {
        float p0 = EXP2(s[nj][mi][0] - mrun[mi]);
        float p1 = EXP2(s[nj][mi][1] - mrun[mi]);
        float p2 = EXP2(s[nj][mi][2] - mrun[mi]);
        float p3 = EXP2(s[nj][mi][3] - mrun[mi]);
        int chunk = nj * 2 + (l4 >> 1);
        char* dst = Pw + prow * 128 + (((chunk ^ (prow & 7)) & 7) << 4) + (l4 & 1) * 8;
        *reinterpret_cast<uint2*>(dst) = make_uint2(pk2(p0, p1), pk2(p2, p3));
      }
    }

    asm volatile("s_waitcnt lgkmcnt(0)" ::: "memory");
    __builtin_amdgcn_sched_barrier(0);

    // P fragments into carry regs (consumed next step); chunk = l4
#pragma unroll
    for (int mi = 0; mi < 2; mi++)
      pf_c[mi] = *reinterpret_cast<const bf16x8*>(Pw + swz128(mi * 16 + l15, l4));
    pend = true;

    __syncthreads();  // drains vmcnt: tile T+1 resident
    buf ^= 1;
  }

  // flush last pending PV
  __builtin_amdgcn_s_setprio(1);
#pragma unroll
  for (int nd = 0; nd < 4; nd++)
#pragma unroll
    for (int mi = 0; mi < 2; mi++)
      oacc[nd][mi] = __builtin_amdgcn_mfma_f32_16x16x32_bf16(
          vf_c[nd], pf_c[mi], oacc[nd][mi], 0, 0, 0);
#pragma unroll
  for (int mi = 0; mi < 2; mi++)
    acc_l[mi] = __builtin_amdgcn_mfma_f32_16x16x32_bf16(onesf, pf_c[mi], acc_l[mi], 0, 0, 0);
  __builtin_amdgcn_s_setprio(0);

  // ---- cross-parity merge: Xo spans both (dead) K buffers, Xml in dead V ----
  char* Xo = lds;                       // 64 rows x 256B fp32
  float* Xml = (float*)(lds + 16384);   // 64 x (m,l)
  if (par == 1) {
#pragma unroll
    for (int mi = 0; mi < 2; mi++) {
      int row = sub * 32 + mi * 16 + l15;
      if (l4 == 0) {
        Xml[row * 2] = mrun[mi];
        Xml[row * 2 + 1] = acc_l[mi][0];
      }
#pragma unroll
      for (int nd = 0; nd < 4; nd++)
        *reinterpret_cast<f32x4*>(Xo + row * 256 + (((nd * 4 + l4) ^ (row & 7)) << 4)) =
            oacc[nd][mi];
    }
  }
  __syncthreads();
  if (par == 0) {
#pragma unroll
    for (int mi = 0; mi < 2; mi++) {
      int row = sub * 32 + mi * 16 + l15;
      float mB = Xml[row * 2], lB = Xml[row * 2 + 1];
      float m = fmaxf(mrun[mi], mB);
      float wA = EXP2(mrun[mi] - m), wB = EXP2(mB - m);
      float linv = 1.0f / (acc_l[mi][0] * wA + lB * wB);
      float fA = wA * linv, fB = wB * linv;
      u16* orow = O + ((size_t)b_ * SEQ + qt * 64 + sub * 32 + mi * 16 + l15) * DIM + h_ * HD;
#pragma unroll
      for (int nd = 0; nd < 4; nd++) {
        f32x4 ob = *reinterpret_cast<const f32x4*>(
            Xo + row * 256 + (((nd * 4 + l4) ^ (row & 7)) << 4));
        float o0 = oacc[nd][mi][0] * fA + ob[0] * fB;
        float o1 = oacc[nd][mi][1] * fA + ob[1] * fB;
        float o2 = oacc[nd][mi][2] * fA + ob[2] * fB;
        float o3 = oacc[nd][mi][3] * fA + ob[3] * fB;
        *reinterpret_cast<uint2*>(orow + nd * 16 + l4 * 4) = make_uint2(pk2(o0, o1), pk2(o2, o3));
      }
    }
  }
}

extern "C" void kernel_launch(void* const* d_in, const int* in_sizes, int n_in,
                              void* d_out, int out_size, void* d_ws, size_t ws_size,
                              hipStream_t stream) {
  const float* x     = (const float*)d_in[0];
  const float* W_qkv = (const float*)d_in[1];
  const float* b_qkv = (const float*)d_in[2];
  const float* W_out = (const float*)d_in[3];
  const float* b_out = (const float*)d_in[4];
  float* out = (float*)d_out;
  char* ws = (char*)d_ws;

  // ws layout (bytes)
  u16* xb    = (u16*)(ws);                               // 8 MB  [4096][1024]
  u16* WqkvT = (u16*)(ws + 8388608);                     // 6 MB  [3072][1024]
  u16* WoutT = (u16*)(ws + 8388608 + 6291456);           // 2 MB  [1024][1024]
  u16* Qb    = (u16*)(ws + 16777216);                    // 8 MB  [32][2048][64]
  u16* Kb    = (u16*)(ws + 16777216 + 8388608);          // 8 MB  [32][2048][64]
  u16* Vtb   = (u16*)(ws + 16777216 + 2 * 8388608);      // 8 MB  [32][64][2048]
  u16* Ob    = (u16*)(ws + 16777216 + 3 * 8388608);      // 8 MB  [4096][1024]

  prep_kernel<<<4096 + 3072 + 1024, 256, 0, stream>>>(x, xb, W_qkv, WqkvT, W_out, WoutT);
  gemm_bt_kernel<0, 128><<<dim3(3 * DIM / 128, BATCH * SEQ / 128), 256, 0, stream>>>(
      xb, WqkvT, b_qkv, nullptr, Qb, Kb, Vtb, BATCH * SEQ, 3 * DIM, DIM);
  attn_kernel<<<1024, 256, 0, stream>>>(Qb, Kb, Vtb, Ob);
  gemm_bt_kernel<1, 64><<<dim3(DIM / 64, BATCH * SEQ / 128), 256, 0, stream>>>(
      Ob, WoutT, b_out, out, nullptr, nullptr, nullptr, BATCH * SEQ, DIM, DIM);
}

// Round 22
// 105.835 us; speedup vs baseline: 1.0699x; 1.0006x over previous
//
#include <hip/hip_runtime.h>
#include <hip/hip_bf16.h>
#include <stdint.h>

#define BATCH 2
#define SEQ   2048
#define DIM   1024
#define NH    16
#define HD    64
#define MVAL  (-10000.0f)

// Native exp2 (raw v_exp_f32, no libm fixup). Fallback: e-domain with __expf.
#if __has_builtin(__builtin_amdgcn_exp2f)
#define EXP2(x) __builtin_amdgcn_exp2f(x)
#define QSCALE  (0.125f * 1.44269504f)   // fold softmax scale AND log2(e) into Q
#else
#define EXP2(x) __expf(x)
#define QSCALE  0.125f
#endif

typedef __attribute__((ext_vector_type(8))) short bf16x8;
typedef __attribute__((ext_vector_type(4))) float f32x4;
typedef unsigned short u16;

static __device__ __forceinline__ u16 f2bf(float f) {
  union { float f; uint32_t u; } c; c.f = f;
  uint32_t x = c.u;
  return (u16)((x + 0x7fffu + ((x >> 16) & 1u)) >> 16);  // RNE
}

static __device__ __forceinline__ uint32_t pk2(float a, float b) {
  __hip_bfloat162 h = __float22bfloat162_rn(make_float2(a, b));
  union { __hip_bfloat162 h; uint32_t u; } c; c.h = h;
  return c.u;
}

// swizzled byte offset within LDS tiles of 128B rows (8 x 16B chunks)
static __device__ __forceinline__ int swz128(int row, int chunk) {
  return row * 128 + (((chunk ^ (row & 7)) & 7) << 4);
}

static __device__ __forceinline__ void gload_lds16(const void* g, void* l) {
  __builtin_amdgcn_global_load_lds((const __attribute__((address_space(1))) void*)g,
                                   (__attribute__((address_space(3))) void*)l, 16, 0, 0);
}

// -------- fused prep: fp32->bf16 convert of x + both weight transposes --------
__global__ void prep_kernel(const float* __restrict__ x, u16* __restrict__ xb,
                            const float* __restrict__ Wqkv, u16* __restrict__ WqkvT,
                            const float* __restrict__ Wout, u16* __restrict__ WoutT) {
  __shared__ float tile[32][33];
  int blk = blockIdx.x, tid = threadIdx.x;
  if (blk < 4096) {
    int i = blk * 256 + tid;
    float4 v = reinterpret_cast<const float4*>(x)[i];
    reinterpret_cast<uint2*>(xb)[i] = make_uint2(pk2(v.x, v.y), pk2(v.z, v.w));
    return;
  }
  const float* in;
  u16* out;
  int C, t;
  if (blk < 4096 + 3072) { t = blk - 4096; in = Wqkv; out = WqkvT; C = 3072; }
  else                   { t = blk - 7168; in = Wout; out = WoutT; C = 1024; }
  int R = DIM;
  int c0 = (t % (C / 32)) * 32, r0 = (t / (C / 32)) * 32;
  int tx = tid & 31, ty = tid >> 5;
#pragma unroll
  for (int i = 0; i < 32; i += 8)
    tile[ty + i][tx] = in[(size_t)(r0 + ty + i) * C + c0 + tx];
  __syncthreads();
#pragma unroll
  for (int i = 0; i < 32; i += 8)
    out[(size_t)(c0 + ty + i) * R + r0 + tx] = f2bf(tile[tx][ty + i]);
}

// ---------------- bf16 GEMM: C = A[M,128/BN tile] x Bt + bias ----------------
// Tile = 128 x BN (BN in {128,64}); 4 waves (wr x wc = 2x2), per-wave 64 x BN/2.
// Swizzled LDS (pre-swizzled gload_lds source + swizzled ds_read_b128).
// SWAPPED mfma operands: lane's acc quad holds 4 consecutive n -> packed stores.
// launch_bounds (256,3): 3 blocks/CU co-resident (grid 768 = 3x256 for gemm0) --
// same occupancy lever that bought attn 8us in r17.
// EPI==0 (BN=128): Q (x QSCALE) / K head-split [bh][s][d]; V transposed [bh][d][s].
// EPI==1: plain fp32 [M][N], 16B stores.
template <int EPI, int BN>
__global__ __launch_bounds__(256, 3) void gemm_bt_kernel(
    const u16* __restrict__ A, const u16* __restrict__ Bt,
    const float* __restrict__ bias, float* __restrict__ Cout,
    u16* __restrict__ Qo, u16* __restrict__ Ko, u16* __restrict__ Vto,
    int M, int N, int K) {
  constexpr int NF = BN / 32;              // n-frags per wave
  __shared__ __align__(16) char lds[16384 + BN * 128];
  char* As = lds;            // 128 rows x 64 bf16, swizzled
  char* Bs = lds + 16384;    // BN rows x 64 bf16, swizzled
  int tid = threadIdx.x;
  int lane = tid & 63, l15 = lane & 15, l4 = lane >> 4;
  int w = tid >> 6, wr = w >> 1, wc = w & 1;
  int m0 = blockIdx.y * 128, n0 = blockIdx.x * BN;
  int srow = tid >> 3, sch = tid & 7;
  int sc_swz = ((sch ^ (srow & 7)) << 3);  // pre-swizzled source chunk (u16 units)

  const u16* Ap = A + (size_t)(m0 + srow) * K + sc_swz;
  const u16* Bp = Bt + (size_t)(n0 + srow) * K + sc_swz;

  f32x4 acc[NF][4] = {};  // acc[nj][mi]: quad holds 4 consecutive n

  for (int k0 = 0; k0 < K; k0 += 64) {
    __syncthreads();
#pragma unroll
    for (int i = 0; i < 4; i++)
      gload_lds16(Ap + (size_t)i * 32 * K + k0, As + i * 4096 + tid * 16);
#pragma unroll
    for (int i = 0; i < BN / 32; i++)
      gload_lds16(Bp + (size_t)i * 32 * K + k0, Bs + i * 4096 + tid * 16);
    __syncthreads();
#pragma unroll
    for (int ks = 0; ks < 2; ks++) {
      int ch = ks * 4 + l4;
      bf16x8 af[4], bfv[NF];
#pragma unroll
      for (int mi = 0; mi < 4; mi++)
        af[mi] = *reinterpret_cast<const bf16x8*>(As + swz128(wr * 64 + mi * 16 + l15, ch));
#pragma unroll
      for (int nj = 0; nj < NF; nj++)
        bfv[nj] = *reinterpret_cast<const bf16x8*>(Bs + swz128(wc * (BN / 2) + nj * 16 + l15, ch));
#pragma unroll
      for (int nj = 0; nj < NF; nj++)
#pragma unroll
        for (int mi = 0; mi < 4; mi++)
          acc[nj][mi] = __builtin_amdgcn_mfma_f32_16x16x32_bf16(bfv[nj], af[mi], acc[nj][mi], 0, 0, 0);
    }
  }

  // epilogue: lane holds C[m][nb..nb+3], m = ..+l15, nb = ..+l4*4
#pragma unroll
  for (int nj = 0; nj < NF; nj++) {
    int nb = n0 + wc * (BN / 2) + nj * 16 + l4 * 4;
    float4 bv = *reinterpret_cast<const float4*>(bias + nb);
#pragma unroll
    for (int mi = 0; mi < 4; mi++) {
      int m = m0 + wr * 64 + mi * 16 + l15;
      f32x4 a = acc[nj][mi];
      float v0 = a[0] + bv.x, v1 = a[1] + bv.y, v2 = a[2] + bv.z, v3 = a[3] + bv.w;
      if (EPI == 1) {
        *reinterpret_cast<float4*>(Cout + (size_t)m * N + nb) = make_float4(v0, v1, v2, v3);
      } else {
        int b = m >> 11, s = m & 2047;
        int sec = nb >> 10, c = nb & 1023, h = c >> 6, d = c & 63;  // sec,h wave-uniform
        size_t bh = (size_t)(b * NH + h);
        if (sec == 0) {
          *reinterpret_cast<uint2*>(Qo + (bh * SEQ + s) * HD + d) =
              make_uint2(pk2(v0 * QSCALE, v1 * QSCALE), pk2(v2 * QSCALE, v3 * QSCALE));
        } else if (sec == 1) {
          *reinterpret_cast<uint2*>(Ko + (bh * SEQ + s) * HD + d) =
              make_uint2(pk2(v0, v1), pk2(v2, v3));
        } else {
          // V transposed: [bh][d][s]; lanes (l15 = s) make 32B contiguous runs
          u16* vt = Vto + (bh * HD + d) * SEQ + s;
          vt[0]       = f2bf(v0);
          vt[SEQ]     = f2bf(v1);
          vt[2 * SEQ] = f2bf(v2);
          vt[3 * SEQ] = f2bf(v3);
        }
      }
    }
  }
}

// ------- causal flash attention: 64-wide KV tiles, 3 blocks/CU + deferred PV -------
// 1024 blocks x 256 thr, 48KB LDS, heavy-first qt (r19-verified best). Wave =
// sub (q 32-half) x par (kv 32-half). Double-buffered gload_lds staging, 1
// barrier/step. Deferred PV carried in regs across the barrier (exact
// reordering). Parity merge through dead K/V regions.
__global__ __launch_bounds__(256, 3) void attn_kernel(
    const u16* __restrict__ Q, const u16* __restrict__ K,
    const u16* __restrict__ Vt, u16* __restrict__ O) {
  __shared__ __align__(16) char lds[49152];  // K 2x8K | V 2x8K | P 4x4K
  int tid = threadIdx.x, lane = tid & 63, w = tid >> 6;
  int l15 = lane & 15, l4 = lane >> 4;
  int sub = w & 1, par = w >> 1;
  int blk = blockIdx.x;
  int bh = (blk & 7) * 4 + ((blk >> 3) & 3);   // XCD-clustered
  int qt = 31 - (blk >> 5);                    // heavy tiles dispatch first
  const u16* Qh = Q + (size_t)bh * SEQ * HD;
  const u16* Kh = K + (size_t)bh * SEQ * HD;
  const u16* Vh = Vt + (size_t)bh * HD * SEQ;
  char* Pw = lds + 32768 + w * 4096;
  int srow = tid >> 3, sch = tid & 7;
  int b_ = bh >> 4, h_ = bh & 15;

  bf16x8 onesf;
#pragma unroll
  for (int j = 0; j < 8; j++) onesf[j] = (short)0x3F80;  // bf16 1.0

  // stage one 64-wide K tile + V^T tile (64 rows x 128B each)
  auto stageKV = [&](int b, int T) {
    const u16* Kt = Kh + (size_t)T * 64 * HD;
    const u16* Vs = Vh + (size_t)T * 64;
    char* Kb = lds + b * 8192;
    char* Vb = lds + 16384 + b * 8192;
#pragma unroll
    for (int i = 0; i < 2; i++) {
      int row = i * 32 + srow;
      int c = (sch ^ (row & 7)) << 3;
      gload_lds16(Kt + (size_t)row * HD + c, Kb + row * 128 + sch * 16);
      gload_lds16(Vs + (size_t)row * SEQ + c, Vb + row * 128 + sch * 16);
    }
  };

  int nT = qt + 1;                      // 64-wide kv tiles covering [0,(qt+1)*64)
  int qb = qt * 64 + sub * 32;

  bf16x8 qf[2][2];
#pragma unroll
  for (int mi = 0; mi < 2; mi++)
#pragma unroll
    for (int ks = 0; ks < 2; ks++)
      qf[mi][ks] = *reinterpret_cast<const bf16x8*>(
          Qh + (size_t)(qb + mi * 16 + l15) * HD + ks * 32 + l4 * 8);

  float mrun[2] = {-1e30f, -1e30f};
  f32x4 oacc[4][2] = {};
  f32x4 acc_l[2] = {};
  bf16x8 pf_c[2], vf_c[4];   // deferred-PV carry registers
  bool pend = false;

  int buf = 0;
  stageKV(0, 0);
  __syncthreads();   // tile 0 resident

  for (int T = 0; T < nT; T++) {
    if (T + 1 < nT) stageKV(buf ^ 1, T + 1);
    char* Kw = lds + buf * 8192;
    char* Vw = lds + 16384 + buf * 8192;
    int kvb = T * 64 + par * 32;

    __builtin_amdgcn_s_setprio(1);
    // deferred PV(T-1): pure-reg MFMAs, overlap with QK's ds_reads
    if (pend) {
#pragma unroll
      for (int nd = 0; nd < 4; nd++)
#pragma unroll
        for (int mi = 0; mi < 2; mi++)
          oacc[nd][mi] = __builtin_amdgcn_mfma_f32_16x16x32_bf16(
              vf_c[nd], pf_c[mi], oacc[nd][mi], 0, 0, 0);
#pragma unroll
      for (int mi = 0; mi < 2; mi++)
        acc_l[mi] = __builtin_amdgcn_mfma_f32_16x16x32_bf16(onesf, pf_c[mi], acc_l[mi], 0, 0, 0);
    }

    // S^T = K . Q^T  (D: row = kv = l4*4+r within nj tile, col = q = l15)
    f32x4 s[2][2] = {};
#pragma unroll
    for (int ks = 0; ks < 2; ks++)
#pragma unroll
      for (int nj = 0; nj < 2; nj++) {
        bf16x8 kf = *reinterpret_cast<const bf16x8*>(
            Kw + swz128(par * 32 + nj * 16 + l15, ks * 4 + l4));
#pragma unroll
        for (int mi = 0; mi < 2; mi++)
          s[nj][mi] = __builtin_amdgcn_mfma_f32_16x16x32_bf16(kf, qf[mi][ks], s[nj][mi], 0, 0, 0);
      }
    __builtin_amdgcn_s_setprio(0);

    // V fragments for THIS tile (consumed by next step's deferred PV)
#pragma unroll
    for (int nd = 0; nd < 4; nd++)
      vf_c[nd] = *reinterpret_cast<const bf16x8*>(
          Vw + swz128(nd * 16 + l15, par * 4 + l4));

    // causal mask: only tiles touching the diagonal
    if (kvb + 31 > qb) {
#pragma unroll
      for (int nj = 0; nj < 2; nj++)
#pragma unroll
        for (int mi = 0; mi < 2; mi++) {
          int qg = qb + mi * 16 + l15;
#pragma unroll
          for (int r = 0; r < 4; r++) {
            int kg = kvb + nj * 16 + l4 * 4 + r;
            if (kg > qg) s[nj][mi][r] = MVAL;
          }
        }
    }

    // tile row-max (q lane-local, reduce across l4: 2 shuffles)
    float mt[2];
#pragma unroll
    for (int mi = 0; mi < 2; mi++) {
      float m = s[0][mi][0];
#pragma unroll
      for (int nj = 0; nj < 2; nj++)
#pragma unroll
        for (int r = 0; r < 4; r++) m = fmaxf(m, s[nj][mi][r]);
      m = fmaxf(m, __shfl_xor(m, 16));
      m = fmaxf(m, __shfl_xor(m, 32));
      mt[mi] = m;
    }

    // defer-max: skip rescale when running max unchanged (exact, THR=0)
    if (!__all((mt[0] <= mrun[0]) & (mt[1] <= mrun[1]))) {
#pragma unroll
      for (int mi = 0; mi < 2; mi++) {
        float mnew = fmaxf(mrun[mi], mt[mi]);
        float alpha = EXP2(mrun[mi] - mnew);
        mrun[mi] = mnew;
#pragma unroll
        for (int nd = 0; nd < 4; nd++)
#pragma unroll
          for (int r = 0; r < 4; r++) oacc[nd][mi][r] *= alpha;
#pragma unroll
        for (int r = 0; r < 4; r++) acc_l[mi][r] *= alpha;
      }
    }

    // P = exp2(s - m) -> bf16 P in per-wave LDS (chunks 0..3, swizzled)
#pragma unroll
    for (int mi = 0; mi < 2; mi++) {
      int prow = mi * 16 + l15;
#pragma unroll
      for (int nj = 0; nj < 2; nj++) {
        float p0 = EXP2(s[nj][mi][0] - mrun[mi]);
        float p1 = EXP2(s[nj][mi][1] - mrun[mi]);
        float p2 = EXP2(s[nj][mi][2] - mrun[mi]);
        float p3 = EXP2(s[nj][mi][3] - mrun[mi]);
        int chunk = nj * 2 + (l4 >> 1);
        char* dst = Pw + prow * 128 + (((chunk ^ (prow & 7)) & 7) << 4) + (l4 & 1) * 8;
        *reinterpret_cast<uint2*>(dst) = make_uint2(pk2(p0, p1), pk2(p2, p3));
      }
    }

    asm volatile("s_waitcnt lgkmcnt(0)" ::: "memory");
    __builtin_amdgcn_sched_barrier(0);

    // P fragments into carry regs (consumed next step); chunk = l4
#pragma unroll
    for (int mi = 0; mi < 2; mi++)
      pf_c[mi] = *reinterpret_cast<const bf16x8*>(Pw + swz128(mi * 16 + l15, l4));
    pend = true;

    __syncthreads();  // drains vmcnt: tile T+1 resident
    buf ^= 1;
  }

  // flush last pending PV
  __builtin_amdgcn_s_setprio(1);
#pragma unroll
  for (int nd = 0; nd < 4; nd++)
#pragma unroll
    for (int mi = 0; mi < 2; mi++)
      oacc[nd][mi] = __builtin_amdgcn_mfma_f32_16x16x32_bf16(
          vf_c[nd], pf_c[mi], oacc[nd][mi], 0, 0, 0);
#pragma unroll
  for (int mi = 0; mi < 2; mi++)
    acc_l[mi] = __builtin_amdgcn_mfma_f32_16x16x32_bf16(onesf, pf_c[mi], acc_l[mi], 0, 0, 0);
  __builtin_amdgcn_s_setprio(0);

  // ---- cross-parity merge: Xo spans both (dead) K buffers, Xml in dead V ----
  char* Xo = lds;                       // 64 rows x 256B fp32
  float* Xml = (float*)(lds + 16384);   // 64 x (m,l)
  if (par == 1) {
#pragma unroll
    for (int mi = 0; mi < 2; mi++) {
      int row = sub * 32 + mi * 16 + l15;
      if (l4 == 0) {
        Xml[row * 2] = mrun[mi];
        Xml[row * 2 + 1] = acc_l[mi][0];
      }
#pragma unroll
      for (int nd = 0; nd < 4; nd++)
        *reinterpret_cast<f32x4*>(Xo + row * 256 + (((nd * 4 + l4) ^ (row & 7)) << 4)) =
            oacc[nd][mi];
    }
  }
  __syncthreads();
  if (par == 0) {
#pragma unroll
    for (int mi = 0; mi < 2; mi++) {
      int row = sub * 32 + mi * 16 + l15;
      float mB = Xml[row * 2], lB = Xml[row * 2 + 1];
      float m = fmaxf(mrun[mi], mB);
      float wA = EXP2(mrun[mi] - m), wB = EXP2(mB - m);
      float linv = 1.0f / (acc_l[mi][0] * wA + lB * wB);
      float fA = wA * linv, fB = wB * linv;
      u16* orow = O + ((size_t)b_ * SEQ + qt * 64 + sub * 32 + mi * 16 + l15) * DIM + h_ * HD;
#pragma unroll
      for (int nd = 0; nd < 4; nd++) {
        f32x4 ob = *reinterpret_cast<const f32x4*>(
            Xo + row * 256 + (((nd * 4 + l4) ^ (row & 7)) << 4));
        float o0 = oacc[nd][mi][0] * fA + ob[0] * fB;
        float o1 = oacc[nd][mi][1] * fA + ob[1] * fB;
        float o2 = oacc[nd][mi][2] * fA + ob[2] * fB;
        float o3 = oacc[nd][mi][3] * fA + ob[3] * fB;
        *reinterpret_cast<uint2*>(orow + nd * 16 + l4 * 4) = make_uint2(pk2(o0, o1), pk2(o2, o3));
      }
    }
  }
}

extern "C" void kernel_launch(void* const* d_in, const int* in_sizes, int n_in,
                              void* d_out, int out_size, void* d_ws, size_t ws_size,
                              hipStream_t stream) {
  const float* x     = (const float*)d_in[0];
  const float* W_qkv = (const float*)d_in[1];
  const float* b_qkv = (const float*)d_in[2];
  const float* W_out = (const float*)d_in[3];
  const float* b_out = (const float*)d_in[4];
  float* out = (float*)d_out;
  char* ws = (char*)d_ws;

  // ws layout (bytes)
  u16* xb    = (u16*)(ws);                               // 8 MB  [4096][1024]
  u16* WqkvT = (u16*)(ws + 8388608);                     // 6 MB  [3072][1024]
  u16* WoutT = (u16*)(ws + 8388608 + 6291456);           // 2 MB  [1024][1024]
  u16* Qb    = (u16*)(ws + 16777216);                    // 8 MB  [32][2048][64]
  u16* Kb    = (u16*)(ws + 16777216 + 8388608);          // 8 MB  [32][2048][64]
  u16* Vtb   = (u16*)(ws + 16777216 + 2 * 8388608);      // 8 MB  [32][64][2048]
  u16* Ob    = (u16*)(ws + 16777216 + 3 * 8388608);      // 8 MB  [4096][1024]

  prep_kernel<<<4096 + 3072 + 1024, 256, 0, stream>>>(x, xb, W_qkv, WqkvT, W_out, WoutT);
  gemm_bt_kernel<0, 128><<<dim3(3 * DIM / 128, BATCH * SEQ / 128), 256, 0, stream>>>(
      xb, WqkvT, b_qkv, nullptr, Qb, Kb, Vtb, BATCH * SEQ, 3 * DIM, DIM);
  attn_kernel<<<1024, 256, 0, stream>>>(Qb, Kb, Vtb, Ob);
  gemm_bt_kernel<1, 64><<<dim3(DIM / 64, BATCH * SEQ / 128), 256, 0, stream>>>(
      Ob, WoutT, b_out, out, nullptr, nullptr, nullptr, BATCH * SEQ, DIM, DIM);
}